// Round 1
// baseline (1830.733 us; speedup 1.0000x reference)
//
#include <hip/hip_runtime.h>

#define HIDN 1024
#define EXPN 2048
#define SDIM 16
#define DTRN 64
#define BBN  4
#define TTN  2048
#define MMN  (BBN*TTN)        // 8192 rows
#define NCHUNK 32
#define CLEN (TTN/NCHUNK)     // 64

typedef unsigned short u16;

static __device__ __forceinline__ float b2f(u16 u) {
    union { unsigned int i; float f; } cv; cv.i = ((unsigned int)u) << 16; return cv.f;
}
static __device__ __forceinline__ u16 f2b(float f) {
    union { float f; unsigned int i; } cv; cv.f = f;
    unsigned int x = cv.i;
    return (u16)((x + 0x7fffu + ((x >> 16) & 1u)) >> 16);
}

// ---------------- A2 = -exp(A_log) * log2(e) ----------------
__global__ __launch_bounds__(256) void k_a2(const float* __restrict__ A_log,
                                            float* __restrict__ A2) {
    int i = blockIdx.x * 256 + threadIdx.x;
    A2[i] = -__expf(A_log[i]) * 1.44269504088896340736f;
}

// ---------------- LayerNorm: x (f32) -> xn (bf16) ----------------
__global__ __launch_bounds__(256) void k_ln(const float* __restrict__ x,
                                            const float* __restrict__ g,
                                            const float* __restrict__ bta,
                                            u16* __restrict__ xn) {
    const int row = blockIdx.x, tid = threadIdx.x;
    const float4 xv = ((const float4*)(x + (size_t)row * HIDN))[tid];
    float s  = xv.x + xv.y + xv.z + xv.w;
    float ss = fmaf(xv.x, xv.x, fmaf(xv.y, xv.y, fmaf(xv.z, xv.z, xv.w * xv.w)));
    #pragma unroll
    for (int o = 32; o > 0; o >>= 1) { s += __shfl_down(s, o); ss += __shfl_down(ss, o); }
    __shared__ float as[4], bs[4];
    const int wid = tid >> 6, lane = tid & 63;
    if (lane == 0) { as[wid] = s; bs[wid] = ss; }
    __syncthreads();
    const float S  = as[0] + as[1] + as[2] + as[3];
    const float SS = bs[0] + bs[1] + bs[2] + bs[3];
    const float mean = S * (1.f / HIDN);
    const float var  = SS * (1.f / HIDN) - mean * mean;
    const float r = rsqrtf(var + 1e-5f);
    const float4 gv = ((const float4*)g)[tid];
    const float4 bv = ((const float4*)bta)[tid];
    ushort4 o;
    o.x = f2b((xv.x - mean) * r * gv.x + bv.x);
    o.y = f2b((xv.y - mean) * r * gv.y + bv.y);
    o.z = f2b((xv.z - mean) * r * gv.z + bv.z);
    o.w = f2b((xv.w - mean) * r * gv.w + bv.w);
    ((ushort4*)(xn + (size_t)row * HIDN))[tid] = o;
}

// ---------------- generic tiled fp32 GEMM ----------------
#define EPI_SPLIT_SILU 0
#define EPI_F32        1
#define EPI_SP_BF16    2
#define EPI_OUT        3

template<int BN, int TN, int EPI, bool ABF16>
__global__ __launch_bounds__(256)
void gemm_k(const void* __restrict__ Ap, const float* __restrict__ Bw,
            const float* __restrict__ bias, void* __restrict__ O0,
            void* __restrict__ O1, const float* __restrict__ res,
            int M, int N, int K) {
    constexpr int BM = 64, BK = 16, TM = 4;
    __shared__ float As[BK][BM + 4];
    __shared__ float Bs[BK][BN + 4];
    const int tid  = threadIdx.x;
    const int brow = blockIdx.y * BM;
    const int bcol = blockIdx.x * BN;
    const int tr = (tid / (BN / TN)) * TM;
    const int tc = (tid % (BN / TN)) * TN;

    float acc[TM][TN];
    #pragma unroll
    for (int m = 0; m < TM; m++)
        #pragma unroll
        for (int n = 0; n < TN; n++) acc[m][n] = 0.f;

    for (int k0 = 0; k0 < K; k0 += BK) {
        { // A tile: 64x16 = 1024 elems, 4/thread
            const int i = tid >> 2;
            const int j = (tid & 3) * 4;
            if constexpr (ABF16) {
                const u16* A = (const u16*)Ap;
                ushort4 v = *(const ushort4*)(A + (size_t)(brow + i) * K + k0 + j);
                As[j + 0][i] = b2f(v.x); As[j + 1][i] = b2f(v.y);
                As[j + 2][i] = b2f(v.z); As[j + 3][i] = b2f(v.w);
            } else {
                const float* A = (const float*)Ap;
                float4 v = *(const float4*)(A + (size_t)(brow + i) * K + k0 + j);
                As[j + 0][i] = v.x; As[j + 1][i] = v.y;
                As[j + 2][i] = v.z; As[j + 3][i] = v.w;
            }
        }
        if constexpr (BN == 64) { // B tile 16x64 = 1024, 4/thread
            const int i = tid >> 4;
            const int j = (tid & 15) * 4;
            float4 v = *(const float4*)(Bw + (size_t)(k0 + i) * N + bcol + j);
            Bs[i][j + 0] = v.x; Bs[i][j + 1] = v.y; Bs[i][j + 2] = v.z; Bs[i][j + 3] = v.w;
        } else { // BN == 16: 256 elems, 1/thread
            const int i = tid >> 4, j = tid & 15;
            Bs[i][j] = Bw[(size_t)(k0 + i) * N + bcol + j];
        }
        __syncthreads();
        #pragma unroll
        for (int k = 0; k < BK; ++k) {
            float a[TM], bb[TN];
            #pragma unroll
            for (int m = 0; m < TM; m++) a[m] = As[k][tr + m];
            #pragma unroll
            for (int n = 0; n < TN; n++) bb[n] = Bs[k][tc + n];
            #pragma unroll
            for (int m = 0; m < TM; m++)
                #pragma unroll
                for (int n = 0; n < TN; n++) acc[m][n] = fmaf(a[m], bb[n], acc[m][n]);
        }
        __syncthreads();
    }
    #pragma unroll
    for (int m = 0; m < TM; m++) {
        const int row = brow + tr + m;
        #pragma unroll
        for (int n = 0; n < TN; n++) {
            const int col = bcol + tc + n;
            float v = acc[m][n] + bias[col];
            if constexpr (EPI == EPI_SPLIT_SILU) {
                float sv = v * (1.f / (1.f + __expf(-v)));
                if (col < EXPN) ((u16*)O0)[(size_t)row * EXPN + col] = f2b(sv);
                else            ((u16*)O1)[(size_t)row * EXPN + (col - EXPN)] = f2b(sv);
            } else if constexpr (EPI == EPI_F32) {
                ((float*)O0)[(size_t)row * N + col] = v;
            } else if constexpr (EPI == EPI_SP_BF16) {
                float sp = fmaxf(v, 0.f) + log1pf(__expf(-fabsf(v)));
                ((u16*)O0)[(size_t)row * N + col] = f2b(sp);
            } else {
                ((float*)O0)[(size_t)row * N + col] = v + res[(size_t)row * N + col];
            }
        }
    }
}

// ---------------- chunked selective scan ----------------
__global__ __launch_bounds__(256)
void k_scan1(const u16* __restrict__ ub, const u16* __restrict__ db,
             const float* __restrict__ Bm, const float* __restrict__ A2,
             float* __restrict__ hend, float* __restrict__ Pp) {
    const int e = blockIdx.x * 256 + threadIdx.x;
    const int c = blockIdx.y, b = blockIdx.z;
    float a2[SDIM], h[SDIM], P[SDIM];
    {
        const float4* ap = (const float4*)(A2 + (size_t)e * SDIM);
        float4 v0 = ap[0], v1 = ap[1], v2 = ap[2], v3 = ap[3];
        a2[0]=v0.x; a2[1]=v0.y; a2[2]=v0.z; a2[3]=v0.w;
        a2[4]=v1.x; a2[5]=v1.y; a2[6]=v1.z; a2[7]=v1.w;
        a2[8]=v2.x; a2[9]=v2.y; a2[10]=v2.z; a2[11]=v2.w;
        a2[12]=v3.x; a2[13]=v3.y; a2[14]=v3.z; a2[15]=v3.w;
    }
    #pragma unroll
    for (int s = 0; s < SDIM; s++) { h[s] = 0.f; P[s] = 1.f; }
    const int t0 = c * CLEN;
    size_t rb = ((size_t)b * TTN + t0) * EXPN + e;
    size_t bb_ = ((size_t)b * TTN + t0) * SDIM;
    for (int tt = 0; tt < CLEN; ++tt) {
        const float d  = b2f(db[rb]);
        const float uv = b2f(ub[rb]);
        const float4* bp = (const float4*)(Bm + bb_);
        float4 b0 = bp[0], b1 = bp[1], b2v = bp[2], b3 = bp[3];
        float bv[SDIM] = { b0.x,b0.y,b0.z,b0.w, b1.x,b1.y,b1.z,b1.w,
                           b2v.x,b2v.y,b2v.z,b2v.w, b3.x,b3.y,b3.z,b3.w };
        const float du = d * uv;
        #pragma unroll
        for (int s = 0; s < SDIM; ++s) {
            float ad = exp2f(d * a2[s]);
            h[s] = fmaf(ad, h[s], du * bv[s]);
            P[s] *= ad;
        }
        rb += EXPN; bb_ += SDIM;
    }
    size_t ob = ((size_t)(b * NCHUNK + c) * SDIM) * EXPN + e;
    #pragma unroll
    for (int s = 0; s < SDIM; ++s) {
        hend[ob + (size_t)s * EXPN] = h[s];
        Pp  [ob + (size_t)s * EXPN] = P[s];
    }
}

__global__ __launch_bounds__(256)
void k_fix(const float* __restrict__ hend, const float* __restrict__ Pp,
           float* __restrict__ hinit) {
    const int i = blockIdx.x * 256 + threadIdx.x;  // over SDIM*EXPN
    const int b = blockIdx.y;
    float hi = 0.f;
    size_t base = ((size_t)b * NCHUNK) * SDIM * EXPN + i;
    for (int cc = 0; cc < NCHUNK; ++cc) {
        size_t idx = base + (size_t)cc * SDIM * EXPN;
        hinit[idx] = hi;
        hi = fmaf(Pp[idx], hi, hend[idx]);
    }
}

__global__ __launch_bounds__(256)
void k_scan2(const u16* __restrict__ ub, const u16* __restrict__ db,
             const u16* __restrict__ sgb, const float* __restrict__ Bm,
             const float* __restrict__ Cm, const float* __restrict__ A2,
             const float* __restrict__ hinit, const float* __restrict__ Dp,
             u16* __restrict__ yb) {
    const int e = blockIdx.x * 256 + threadIdx.x;
    const int c = blockIdx.y, b = blockIdx.z;
    float a2[SDIM], h[SDIM];
    {
        const float4* ap = (const float4*)(A2 + (size_t)e * SDIM);
        float4 v0 = ap[0], v1 = ap[1], v2 = ap[2], v3 = ap[3];
        a2[0]=v0.x; a2[1]=v0.y; a2[2]=v0.z; a2[3]=v0.w;
        a2[4]=v1.x; a2[5]=v1.y; a2[6]=v1.z; a2[7]=v1.w;
        a2[8]=v2.x; a2[9]=v2.y; a2[10]=v2.z; a2[11]=v2.w;
        a2[12]=v3.x; a2[13]=v3.y; a2[14]=v3.z; a2[15]=v3.w;
    }
    {
        size_t hb = ((size_t)(b * NCHUNK + c) * SDIM) * EXPN + e;
        #pragma unroll
        for (int s = 0; s < SDIM; s++) h[s] = hinit[hb + (size_t)s * EXPN];
    }
    const float dpe = Dp[e];
    const int t0 = c * CLEN;
    size_t rb = ((size_t)b * TTN + t0) * EXPN + e;
    size_t bb_ = ((size_t)b * TTN + t0) * SDIM;
    for (int tt = 0; tt < CLEN; ++tt) {
        const float d   = b2f(db[rb]);
        const float uv  = b2f(ub[rb]);
        const float sgv = b2f(sgb[rb]);
        const float4* bp = (const float4*)(Bm + bb_);
        const float4* cp = (const float4*)(Cm + bb_);
        float4 b0 = bp[0], b1 = bp[1], b2v = bp[2], b3 = bp[3];
        float4 c0 = cp[0], c1 = cp[1], c2v = cp[2], c3 = cp[3];
        float bv[SDIM] = { b0.x,b0.y,b0.z,b0.w, b1.x,b1.y,b1.z,b1.w,
                           b2v.x,b2v.y,b2v.z,b2v.w, b3.x,b3.y,b3.z,b3.w };
        float cv[SDIM] = { c0.x,c0.y,c0.z,c0.w, c1.x,c1.y,c1.z,c1.w,
                           c2v.x,c2v.y,c2v.z,c2v.w, c3.x,c3.y,c3.z,c3.w };
        const float du = d * uv;
        float yt = 0.f;
        #pragma unroll
        for (int s = 0; s < SDIM; ++s) {
            float ad = exp2f(d * a2[s]);
            h[s] = fmaf(ad, h[s], du * bv[s]);
            yt = fmaf(cv[s], h[s], yt);
        }
        yb[rb] = f2b(fmaf(uv, dpe, yt) * sgv);
        rb += EXPN; bb_ += SDIM;
    }
}

// ---------------- launch ----------------
extern "C" void kernel_launch(void* const* d_in, const int* in_sizes, int n_in,
                              void* d_out, int out_size, void* d_ws, size_t ws_size,
                              hipStream_t stream) {
    const float* x     = (const float*)d_in[0];
    const float* ln_g  = (const float*)d_in[1];
    const float* ln_b  = (const float*)d_in[2];
    const float* W_in  = (const float*)d_in[3];
    const float* b_in  = (const float*)d_in[4];
    const float* W_del = (const float*)d_in[5];
    const float* b_del = (const float*)d_in[6];
    const float* W_dt  = (const float*)d_in[7];
    const float* b_dt  = (const float*)d_in[8];
    const float* W_B   = (const float*)d_in[9];
    const float* b_B   = (const float*)d_in[10];
    const float* W_C   = (const float*)d_in[11];
    const float* b_C   = (const float*)d_in[12];
    const float* A_log = (const float*)d_in[13];
    const float* Dp    = (const float*)d_in[14];
    const float* W_out = (const float*)d_in[15];
    const float* b_out = (const float*)d_in[16];
    float* out = (float*)d_out;

    char* p = (char*)d_ws;
    auto alloc = [&](size_t bytes) {
        char* r = p; p += (bytes + 255) & ~(size_t)255; return (void*)r;
    };
    u16* xn   = (u16*)alloc((size_t)MMN * HIDN * 2);
    u16* u    = (u16*)alloc((size_t)MMN * EXPN * 2);
    u16* sg   = (u16*)alloc((size_t)MMN * EXPN * 2);
    u16* dl   = (u16*)alloc((size_t)MMN * EXPN * 2);
    u16* y    = (u16*)alloc((size_t)MMN * EXPN * 2);
    float* t1 = (float*)alloc((size_t)MMN * DTRN * 4);
    float* Bm = (float*)alloc((size_t)MMN * SDIM * 4);
    float* Cm = (float*)alloc((size_t)MMN * SDIM * 4);
    float* A2 = (float*)alloc((size_t)EXPN * SDIM * 4);
    const size_t hsz = (size_t)BBN * NCHUNK * EXPN * SDIM * 4;
    float* hend  = (float*)alloc(hsz);
    float* Pp    = (float*)alloc(hsz);
    float* hinit = (float*)alloc(hsz);

    k_a2<<<dim3(EXPN * SDIM / 256), 256, 0, stream>>>(A_log, A2);
    k_ln<<<dim3(MMN), 256, 0, stream>>>(x, ln_g, ln_b, xn);
    // xp = xn @ W_in + b_in ; u = silu(left), sg = silu(right)
    gemm_k<64, 4, EPI_SPLIT_SILU, true><<<dim3(2 * EXPN / 64, MMN / 64), 256, 0, stream>>>(
        xn, W_in, b_in, u, sg, nullptr, MMN, 2 * EXPN, HIDN);
    // t1 = u @ W_del + b_del
    gemm_k<64, 4, EPI_F32, true><<<dim3(DTRN / 64, MMN / 64), 256, 0, stream>>>(
        u, W_del, b_del, t1, nullptr, nullptr, MMN, DTRN, EXPN);
    // Bm, Cm
    gemm_k<16, 1, EPI_F32, true><<<dim3(1, MMN / 64), 256, 0, stream>>>(
        u, W_B, b_B, Bm, nullptr, nullptr, MMN, SDIM, EXPN);
    gemm_k<16, 1, EPI_F32, true><<<dim3(1, MMN / 64), 256, 0, stream>>>(
        u, W_C, b_C, Cm, nullptr, nullptr, MMN, SDIM, EXPN);
    // delta = softplus(t1 @ W_dt + b_dt)
    gemm_k<64, 4, EPI_SP_BF16, false><<<dim3(EXPN / 64, MMN / 64), 256, 0, stream>>>(
        t1, W_dt, b_dt, dl, nullptr, nullptr, MMN, EXPN, DTRN);
    // chunked selective scan
    k_scan1<<<dim3(EXPN / 256, NCHUNK, BBN), 256, 0, stream>>>(u, dl, Bm, A2, hend, Pp);
    k_fix<<<dim3(SDIM * EXPN / 256, BBN), 256, 0, stream>>>(hend, Pp, hinit);
    k_scan2<<<dim3(EXPN / 256, NCHUNK, BBN), 256, 0, stream>>>(u, dl, sg, Bm, Cm, A2, hinit, Dp, y);
    // out = y @ W_out + b_out + x
    gemm_k<64, 4, EPI_OUT, true><<<dim3(HIDN / 64, MMN / 64), 256, 0, stream>>>(
        y, W_out, b_out, out, nullptr, x, MMN, HIDN, EXPN);
}

// Round 2
// 736.253 us; speedup vs baseline: 2.4866x; 2.4866x over previous
//
#include <hip/hip_runtime.h>

#define HIDN 1024
#define EXPN 2048
#define SDIM 16
#define DTRN 64
#define BBN  4
#define TTN  2048
#define MMN  (BBN*TTN)        // 8192 rows
#define NCHUNK 32
#define CLEN (TTN/NCHUNK)     // 64

typedef unsigned short u16;
typedef __bf16 bf16x8 __attribute__((ext_vector_type(8)));
typedef float f32x4 __attribute__((ext_vector_type(4)));

static __device__ __forceinline__ float b2f(u16 u) {
    union { unsigned int i; float f; } cv; cv.i = ((unsigned int)u) << 16; return cv.f;
}
static __device__ __forceinline__ u16 f2b(float f) {
    union { float f; unsigned int i; } cv; cv.f = f;
    unsigned int x = cv.i;
    return (u16)((x + 0x7fffu + ((x >> 16) & 1u)) >> 16);
}

// ---------------- A2 = -exp(A_log) * log2(e) ----------------
__global__ __launch_bounds__(256) void k_a2(const float* __restrict__ A_log,
                                            float* __restrict__ A2) {
    int i = blockIdx.x * 256 + threadIdx.x;
    A2[i] = -__expf(A_log[i]) * 1.44269504088896340736f;
}

// ---------------- weight transpose f32 (K,N) -> bf16 (N,K) ----------------
__global__ __launch_bounds__(256)
void k_tr(const float* __restrict__ W, u16* __restrict__ Wt, int K, int N) {
    __shared__ float t[64][65];
    const int bk = blockIdx.y << 6, bn = blockIdx.x << 6;
    const int r0 = threadIdx.x >> 4, c0 = (threadIdx.x & 15) << 2;
    #pragma unroll
    for (int i = 0; i < 4; ++i) {
        float4 v = *(const float4*)(W + (size_t)(bk + r0 + i * 16) * N + bn + c0);
        t[r0 + i * 16][c0 + 0] = v.x; t[r0 + i * 16][c0 + 1] = v.y;
        t[r0 + i * 16][c0 + 2] = v.z; t[r0 + i * 16][c0 + 3] = v.w;
    }
    __syncthreads();
    #pragma unroll
    for (int i = 0; i < 4; ++i) {
        const int n = r0 + i * 16;
        ushort4 o;
        o.x = f2b(t[c0 + 0][n]); o.y = f2b(t[c0 + 1][n]);
        o.z = f2b(t[c0 + 2][n]); o.w = f2b(t[c0 + 3][n]);
        *(ushort4*)(Wt + (size_t)(bn + n) * K + bk + c0) = o;
    }
}

// ---------------- LayerNorm: x (f32) -> xn (bf16) ----------------
__global__ __launch_bounds__(256) void k_ln(const float* __restrict__ x,
                                            const float* __restrict__ g,
                                            const float* __restrict__ bta,
                                            u16* __restrict__ xn) {
    const int row = blockIdx.x, tid = threadIdx.x;
    const float4 xv = ((const float4*)(x + (size_t)row * HIDN))[tid];
    float s  = xv.x + xv.y + xv.z + xv.w;
    float ss = fmaf(xv.x, xv.x, fmaf(xv.y, xv.y, fmaf(xv.z, xv.z, xv.w * xv.w)));
    #pragma unroll
    for (int o = 32; o > 0; o >>= 1) { s += __shfl_down(s, o); ss += __shfl_down(ss, o); }
    __shared__ float as[4], bs[4];
    const int wid = tid >> 6, lane = tid & 63;
    if (lane == 0) { as[wid] = s; bs[wid] = ss; }
    __syncthreads();
    const float S  = as[0] + as[1] + as[2] + as[3];
    const float SS = bs[0] + bs[1] + bs[2] + bs[3];
    const float mean = S * (1.f / HIDN);
    const float var  = SS * (1.f / HIDN) - mean * mean;
    const float r = rsqrtf(var + 1e-5f);
    const float4 gv = ((const float4*)g)[tid];
    const float4 bv = ((const float4*)bta)[tid];
    ushort4 o;
    o.x = f2b((xv.x - mean) * r * gv.x + bv.x);
    o.y = f2b((xv.y - mean) * r * gv.y + bv.y);
    o.z = f2b((xv.z - mean) * r * gv.z + bv.z);
    o.w = f2b((xv.w - mean) * r * gv.w + bv.w);
    ((ushort4*)(xn + (size_t)row * HIDN))[tid] = o;
}

// ---------------- MFMA bf16 GEMM: C = A @ Bt^T (m97 structure) ----------------
// A: (M,K) bf16 row-major; Bt: (N,K) bf16 row-major. 128x128 tile, BK=32,
// 4 waves in 2x2, each wave 64x64 = 4x4 frags of 16x16x32.
#define MEPI_SPLIT_SILU 0
#define MEPI_OUT        1

template<int EPI>
__global__ __launch_bounds__(256)
void mgemm(const u16* __restrict__ A, const u16* __restrict__ Bt,
           const float* __restrict__ bias, void* __restrict__ O0,
           void* __restrict__ O1, const float* __restrict__ res,
           int N, int K) {
    __shared__ u16 As[128 * 32];
    __shared__ u16 Bs[128 * 32];
    const int tid  = threadIdx.x;
    const int wave = tid >> 6, lane = tid & 63;
    const int brow = blockIdx.y * 128, bcol = blockIdx.x * 128;
    const int wm = wave >> 1, wn = wave & 1;
    const int r  = lane & 15, kh = lane >> 4;

    f32x4 acc[4][4];
    #pragma unroll
    for (int m = 0; m < 4; m++)
        #pragma unroll
        for (int n = 0; n < 4; n++) acc[m][n] = (f32x4){0.f, 0.f, 0.f, 0.f};

    // staging: slot s (0..511) covers row s/4 of the tile, bytes (s%4)*16.
    const u16* ga0 = A  + (size_t)(brow +      (tid >> 2)) * K + (tid & 3) * 8;
    const u16* ga1 = A  + (size_t)(brow + 64 + (tid >> 2)) * K + (tid & 3) * 8;
    const u16* gb0 = Bt + (size_t)(bcol +      (tid >> 2)) * K + (tid & 3) * 8;
    const u16* gb1 = Bt + (size_t)(bcol + 64 + (tid >> 2)) * K + (tid & 3) * 8;
    u16* lA0 = As + (wave * 64) * 8;
    u16* lA1 = As + (256 + wave * 64) * 8;
    u16* lB0 = Bs + (wave * 64) * 8;
    u16* lB1 = Bs + (256 + wave * 64) * 8;

    for (int k0 = 0; k0 < K; k0 += 32) {
        __syncthreads();  // prior iteration's LDS reads done
        __builtin_amdgcn_global_load_lds((const __attribute__((address_space(1))) void*)(ga0 + k0),
                                         (__attribute__((address_space(3))) void*)lA0, 16, 0, 0);
        __builtin_amdgcn_global_load_lds((const __attribute__((address_space(1))) void*)(ga1 + k0),
                                         (__attribute__((address_space(3))) void*)lA1, 16, 0, 0);
        __builtin_amdgcn_global_load_lds((const __attribute__((address_space(1))) void*)(gb0 + k0),
                                         (__attribute__((address_space(3))) void*)lB0, 16, 0, 0);
        __builtin_amdgcn_global_load_lds((const __attribute__((address_space(1))) void*)(gb1 + k0),
                                         (__attribute__((address_space(3))) void*)lB1, 16, 0, 0);
        __syncthreads();  // compiler drains vmcnt before s_barrier
        bf16x8 af[4], bfr[4];
        #pragma unroll
        for (int mf = 0; mf < 4; ++mf)
            af[mf] = *(const bf16x8*)(As + ((wm * 64 + mf * 16 + r) * 32 + kh * 8));
        #pragma unroll
        for (int nf = 0; nf < 4; ++nf)
            bfr[nf] = *(const bf16x8*)(Bs + ((wn * 64 + nf * 16 + r) * 32 + kh * 8));
        #pragma unroll
        for (int mf = 0; mf < 4; ++mf)
            #pragma unroll
            for (int nf = 0; nf < 4; ++nf)
                acc[mf][nf] = __builtin_amdgcn_mfma_f32_16x16x32_bf16(af[mf], bfr[nf], acc[mf][nf], 0, 0, 0);
    }

    const int orow = brow + wm * 64 + kh * 4;   // + mf*16 + j
    const int ocol = bcol + wn * 64 + r;        // + nf*16
    if constexpr (EPI == MEPI_SPLIT_SILU) {
        u16* dst; int cb;
        if (bcol < EXPN) { dst = (u16*)O0; cb = ocol; }
        else             { dst = (u16*)O1; cb = ocol - EXPN; }
        #pragma unroll
        for (int mf = 0; mf < 4; ++mf)
            #pragma unroll
            for (int nf = 0; nf < 4; ++nf)
                #pragma unroll
                for (int j = 0; j < 4; ++j) {
                    const int row = orow + mf * 16 + j;
                    const int col = ocol + nf * 16;
                    float v = acc[mf][nf][j] + bias[col];
                    float sv = v * (1.f / (1.f + __expf(-v)));
                    dst[(size_t)row * EXPN + cb + nf * 16] = f2b(sv);
                }
    } else {
        float* o = (float*)O0;
        #pragma unroll
        for (int mf = 0; mf < 4; ++mf)
            #pragma unroll
            for (int nf = 0; nf < 4; ++nf)
                #pragma unroll
                for (int j = 0; j < 4; ++j) {
                    const int row = orow + mf * 16 + j;
                    const int col = ocol + nf * 16;
                    o[(size_t)row * N + col] = acc[mf][nf][j] + bias[col] + res[(size_t)row * N + col];
                }
    }
}

// ---------------- generic tiled fp32 GEMM (small GEMMs) ----------------
#define EPI_SPLIT_SILU 0
#define EPI_F32        1
#define EPI_SP_BF16    2
#define EPI_OUT        3

template<int BN, int TN, int EPI, bool ABF16>
__global__ __launch_bounds__(256)
void gemm_k(const void* __restrict__ Ap, const float* __restrict__ Bw,
            const float* __restrict__ bias, void* __restrict__ O0,
            void* __restrict__ O1, const float* __restrict__ res,
            int M, int N, int K) {
    constexpr int BM = 64, BK = 16, TM = 4;
    __shared__ float As[BK][BM + 4];
    __shared__ float Bs[BK][BN + 4];
    const int tid  = threadIdx.x;
    const int brow = blockIdx.y * BM;
    const int bcol = blockIdx.x * BN;
    const int tr = (tid / (BN / TN)) * TM;
    const int tc = (tid % (BN / TN)) * TN;

    float acc[TM][TN];
    #pragma unroll
    for (int m = 0; m < TM; m++)
        #pragma unroll
        for (int n = 0; n < TN; n++) acc[m][n] = 0.f;

    for (int k0 = 0; k0 < K; k0 += BK) {
        {
            const int i = tid >> 2;
            const int j = (tid & 3) * 4;
            if constexpr (ABF16) {
                const u16* A = (const u16*)Ap;
                ushort4 v = *(const ushort4*)(A + (size_t)(brow + i) * K + k0 + j);
                As[j + 0][i] = b2f(v.x); As[j + 1][i] = b2f(v.y);
                As[j + 2][i] = b2f(v.z); As[j + 3][i] = b2f(v.w);
            } else {
                const float* A = (const float*)Ap;
                float4 v = *(const float4*)(A + (size_t)(brow + i) * K + k0 + j);
                As[j + 0][i] = v.x; As[j + 1][i] = v.y;
                As[j + 2][i] = v.z; As[j + 3][i] = v.w;
            }
        }
        if constexpr (BN == 64) {
            const int i = tid >> 4;
            const int j = (tid & 15) * 4;
            float4 v = *(const float4*)(Bw + (size_t)(k0 + i) * N + bcol + j);
            Bs[i][j + 0] = v.x; Bs[i][j + 1] = v.y; Bs[i][j + 2] = v.z; Bs[i][j + 3] = v.w;
        } else {
            const int i = tid >> 4, j = tid & 15;
            Bs[i][j] = Bw[(size_t)(k0 + i) * N + bcol + j];
        }
        __syncthreads();
        #pragma unroll
        for (int k = 0; k < BK; ++k) {
            float a[TM], bb[TN];
            #pragma unroll
            for (int m = 0; m < TM; m++) a[m] = As[k][tr + m];
            #pragma unroll
            for (int n = 0; n < TN; n++) bb[n] = Bs[k][tc + n];
            #pragma unroll
            for (int m = 0; m < TM; m++)
                #pragma unroll
                for (int n = 0; n < TN; n++) acc[m][n] = fmaf(a[m], bb[n], acc[m][n]);
        }
        __syncthreads();
    }
    #pragma unroll
    for (int m = 0; m < TM; m++) {
        const int row = brow + tr + m;
        #pragma unroll
        for (int n = 0; n < TN; n++) {
            const int col = bcol + tc + n;
            float v = acc[m][n] + bias[col];
            if constexpr (EPI == EPI_SPLIT_SILU) {
                float sv = v * (1.f / (1.f + __expf(-v)));
                if (col < EXPN) ((u16*)O0)[(size_t)row * EXPN + col] = f2b(sv);
                else            ((u16*)O1)[(size_t)row * EXPN + (col - EXPN)] = f2b(sv);
            } else if constexpr (EPI == EPI_F32) {
                ((float*)O0)[(size_t)row * N + col] = v;
            } else if constexpr (EPI == EPI_SP_BF16) {
                float sp = fmaxf(v, 0.f) + log1pf(__expf(-fabsf(v)));
                ((u16*)O0)[(size_t)row * N + col] = f2b(sp);
            } else {
                ((float*)O0)[(size_t)row * N + col] = v + res[(size_t)row * N + col];
            }
        }
    }
}

// ---------------- chunked selective scan ----------------
__global__ __launch_bounds__(256)
void k_scan1(const u16* __restrict__ ub, const u16* __restrict__ db,
             const float* __restrict__ Bm, const float* __restrict__ A2,
             float* __restrict__ hend, float* __restrict__ Pp) {
    const int e = blockIdx.x * 256 + threadIdx.x;
    const int c = blockIdx.y, b = blockIdx.z;
    float a2[SDIM], h[SDIM], P[SDIM];
    {
        const float4* ap = (const float4*)(A2 + (size_t)e * SDIM);
        float4 v0 = ap[0], v1 = ap[1], v2 = ap[2], v3 = ap[3];
        a2[0]=v0.x; a2[1]=v0.y; a2[2]=v0.z; a2[3]=v0.w;
        a2[4]=v1.x; a2[5]=v1.y; a2[6]=v1.z; a2[7]=v1.w;
        a2[8]=v2.x; a2[9]=v2.y; a2[10]=v2.z; a2[11]=v2.w;
        a2[12]=v3.x; a2[13]=v3.y; a2[14]=v3.z; a2[15]=v3.w;
    }
    #pragma unroll
    for (int s = 0; s < SDIM; s++) { h[s] = 0.f; P[s] = 1.f; }
    const int t0 = c * CLEN;
    size_t rb = ((size_t)b * TTN + t0) * EXPN + e;
    size_t bb_ = ((size_t)b * TTN + t0) * SDIM;
    for (int tt = 0; tt < CLEN; ++tt) {
        const float d  = b2f(db[rb]);
        const float uv = b2f(ub[rb]);
        const float4* bp = (const float4*)(Bm + bb_);
        float4 b0 = bp[0], b1 = bp[1], b2v = bp[2], b3 = bp[3];
        float bv[SDIM] = { b0.x,b0.y,b0.z,b0.w, b1.x,b1.y,b1.z,b1.w,
                           b2v.x,b2v.y,b2v.z,b2v.w, b3.x,b3.y,b3.z,b3.w };
        const float du = d * uv;
        #pragma unroll
        for (int s = 0; s < SDIM; ++s) {
            float ad = exp2f(d * a2[s]);
            h[s] = fmaf(ad, h[s], du * bv[s]);
            P[s] *= ad;
        }
        rb += EXPN; bb_ += SDIM;
    }
    size_t ob = ((size_t)(b * NCHUNK + c) * SDIM) * EXPN + e;
    #pragma unroll
    for (int s = 0; s < SDIM; ++s) {
        hend[ob + (size_t)s * EXPN] = h[s];
        Pp  [ob + (size_t)s * EXPN] = P[s];
    }
}

__global__ __launch_bounds__(256)
void k_fix(const float* __restrict__ hend, const float* __restrict__ Pp,
           float* __restrict__ hinit) {
    const int i = blockIdx.x * 256 + threadIdx.x;  // over SDIM*EXPN
    const int b = blockIdx.y;
    float hi = 0.f;
    size_t base = ((size_t)b * NCHUNK) * SDIM * EXPN + i;
    for (int cc = 0; cc < NCHUNK; ++cc) {
        size_t idx = base + (size_t)cc * SDIM * EXPN;
        hinit[idx] = hi;
        hi = fmaf(Pp[idx], hi, hend[idx]);
    }
}

__global__ __launch_bounds__(256)
void k_scan2(const u16* __restrict__ ub, const u16* __restrict__ db,
             const u16* __restrict__ sgb, const float* __restrict__ Bm,
             const float* __restrict__ Cm, const float* __restrict__ A2,
             const float* __restrict__ hinit, const float* __restrict__ Dp,
             u16* __restrict__ yb) {
    const int e = blockIdx.x * 256 + threadIdx.x;
    const int c = blockIdx.y, b = blockIdx.z;
    float a2[SDIM], h[SDIM];
    {
        const float4* ap = (const float4*)(A2 + (size_t)e * SDIM);
        float4 v0 = ap[0], v1 = ap[1], v2 = ap[2], v3 = ap[3];
        a2[0]=v0.x; a2[1]=v0.y; a2[2]=v0.z; a2[3]=v0.w;
        a2[4]=v1.x; a2[5]=v1.y; a2[6]=v1.z; a2[7]=v1.w;
        a2[8]=v2.x; a2[9]=v2.y; a2[10]=v2.z; a2[11]=v2.w;
        a2[12]=v3.x; a2[13]=v3.y; a2[14]=v3.z; a2[15]=v3.w;
    }
    {
        size_t hb = ((size_t)(b * NCHUNK + c) * SDIM) * EXPN + e;
        #pragma unroll
        for (int s = 0; s < SDIM; s++) h[s] = hinit[hb + (size_t)s * EXPN];
    }
    const float dpe = Dp[e];
    const int t0 = c * CLEN;
    size_t rb = ((size_t)b * TTN + t0) * EXPN + e;
    size_t bb_ = ((size_t)b * TTN + t0) * SDIM;
    for (int tt = 0; tt < CLEN; ++tt) {
        const float d   = b2f(db[rb]);
        const float uv  = b2f(ub[rb]);
        const float sgv = b2f(sgb[rb]);
        const float4* bp = (const float4*)(Bm + bb_);
        const float4* cp = (const float4*)(Cm + bb_);
        float4 b0 = bp[0], b1 = bp[1], b2v = bp[2], b3 = bp[3];
        float4 c0 = cp[0], c1 = cp[1], c2v = cp[2], c3 = cp[3];
        float bv[SDIM] = { b0.x,b0.y,b0.z,b0.w, b1.x,b1.y,b1.z,b1.w,
                           b2v.x,b2v.y,b2v.z,b2v.w, b3.x,b3.y,b3.z,b3.w };
        float cv[SDIM] = { c0.x,c0.y,c0.z,c0.w, c1.x,c1.y,c1.z,c1.w,
                           c2v.x,c2v.y,c2v.z,c2v.w, c3.x,c3.y,c3.z,c3.w };
        const float du = d * uv;
        float yt = 0.f;
        #pragma unroll
        for (int s = 0; s < SDIM; ++s) {
            float ad = exp2f(d * a2[s]);
            h[s] = fmaf(ad, h[s], du * bv[s]);
            yt = fmaf(cv[s], h[s], yt);
        }
        yb[rb] = f2b(fmaf(uv, dpe, yt) * sgv);
        rb += EXPN; bb_ += SDIM;
    }
}

// ---------------- launch ----------------
extern "C" void kernel_launch(void* const* d_in, const int* in_sizes, int n_in,
                              void* d_out, int out_size, void* d_ws, size_t ws_size,
                              hipStream_t stream) {
    const float* x     = (const float*)d_in[0];
    const float* ln_g  = (const float*)d_in[1];
    const float* ln_b  = (const float*)d_in[2];
    const float* W_in  = (const float*)d_in[3];
    const float* b_in  = (const float*)d_in[4];
    const float* W_del = (const float*)d_in[5];
    const float* b_del = (const float*)d_in[6];
    const float* W_dt  = (const float*)d_in[7];
    const float* b_dt  = (const float*)d_in[8];
    const float* W_B   = (const float*)d_in[9];
    const float* b_B   = (const float*)d_in[10];
    const float* W_C   = (const float*)d_in[11];
    const float* b_C   = (const float*)d_in[12];
    const float* A_log = (const float*)d_in[13];
    const float* Dp    = (const float*)d_in[14];
    const float* W_out = (const float*)d_in[15];
    const float* b_out = (const float*)d_in[16];
    float* out = (float*)d_out;

    char* p = (char*)d_ws;
    auto alloc = [&](size_t bytes) {
        char* r = p; p += (bytes + 255) & ~(size_t)255; return (void*)r;
    };
    u16* xn   = (u16*)alloc((size_t)MMN * HIDN * 2);
    u16* u    = (u16*)alloc((size_t)MMN * EXPN * 2);
    u16* sg   = (u16*)alloc((size_t)MMN * EXPN * 2);
    u16* dl   = (u16*)alloc((size_t)MMN * EXPN * 2);
    u16* y    = (u16*)alloc((size_t)MMN * EXPN * 2);
    float* t1 = (float*)alloc((size_t)MMN * DTRN * 4);
    float* Bm = (float*)alloc((size_t)MMN * SDIM * 4);
    float* Cm = (float*)alloc((size_t)MMN * SDIM * 4);
    float* A2 = (float*)alloc((size_t)EXPN * SDIM * 4);
    u16* Wt_in  = (u16*)alloc((size_t)(2 * EXPN) * HIDN * 2);
    u16* Wt_out = (u16*)alloc((size_t)HIDN * EXPN * 2);
    const size_t hsz = (size_t)BBN * NCHUNK * EXPN * SDIM * 4;
    float* hend  = (float*)alloc(hsz);
    float* Pp    = (float*)alloc(hsz);
    float* hinit = (float*)alloc(hsz);

    k_a2<<<dim3(EXPN * SDIM / 256), 256, 0, stream>>>(A_log, A2);
    k_ln<<<dim3(MMN), 256, 0, stream>>>(x, ln_g, ln_b, xn);
    // weight conversions: W_in (HIDN, 2E) -> Wt_in (2E, HIDN); W_out (E, HIDN) -> Wt_out (HIDN, E)
    k_tr<<<dim3(2 * EXPN / 64, HIDN / 64), 256, 0, stream>>>(W_in, Wt_in, HIDN, 2 * EXPN);
    k_tr<<<dim3(HIDN / 64, EXPN / 64), 256, 0, stream>>>(W_out, Wt_out, EXPN, HIDN);

    // xp = xn @ W_in + b_in ; u = silu(left), sg = silu(right)   [MFMA]
    mgemm<MEPI_SPLIT_SILU><<<dim3(2 * EXPN / 128, MMN / 128), 256, 0, stream>>>(
        xn, Wt_in, b_in, u, sg, nullptr, 2 * EXPN, HIDN);
    // t1 = u @ W_del + b_del
    gemm_k<64, 4, EPI_F32, true><<<dim3(DTRN / 64, MMN / 64), 256, 0, stream>>>(
        u, W_del, b_del, t1, nullptr, nullptr, MMN, DTRN, EXPN);
    // Bm, Cm
    gemm_k<16, 1, EPI_F32, true><<<dim3(1, MMN / 64), 256, 0, stream>>>(
        u, W_B, b_B, Bm, nullptr, nullptr, MMN, SDIM, EXPN);
    gemm_k<16, 1, EPI_F32, true><<<dim3(1, MMN / 64), 256, 0, stream>>>(
        u, W_C, b_C, Cm, nullptr, nullptr, MMN, SDIM, EXPN);
    // delta = softplus(t1 @ W_dt + b_dt)
    gemm_k<64, 4, EPI_SP_BF16, false><<<dim3(EXPN / 64, MMN / 64), 256, 0, stream>>>(
        t1, W_dt, b_dt, dl, nullptr, nullptr, MMN, EXPN, DTRN);
    // chunked selective scan
    k_scan1<<<dim3(EXPN / 256, NCHUNK, BBN), 256, 0, stream>>>(u, dl, Bm, A2, hend, Pp);
    k_fix<<<dim3(SDIM * EXPN / 256, BBN), 256, 0, stream>>>(hend, Pp, hinit);
    k_scan2<<<dim3(EXPN / 256, NCHUNK, BBN), 256, 0, stream>>>(u, dl, sg, Bm, Cm, A2, hinit, Dp, y);
    // out = y @ W_out + b_out + x   [MFMA]
    mgemm<MEPI_OUT><<<dim3(HIDN / 128, MMN / 128), 256, 0, stream>>>(
        y, Wt_out, b_out, out, nullptr, x, HIDN, EXPN);
}

// Round 3
// 437.732 us; speedup vs baseline: 4.1823x; 1.6820x over previous
//
#include <hip/hip_runtime.h>

#define HIDN 1024
#define EXPN 2048
#define SDIM 16
#define DTRN 64
#define BBN  4
#define TTN  2048
#define MMN  (BBN*TTN)        // 8192 rows
#define NCHUNK 32
#define CLEN (TTN/NCHUNK)     // 64
#define KSPL 8                // split-K chunks for k_proj
#define KCH  (EXPN/KSPL)      // 256

typedef unsigned short u16;
typedef __bf16 bf16x8 __attribute__((ext_vector_type(8)));
typedef float f32x4 __attribute__((ext_vector_type(4)));

static __device__ __forceinline__ float b2f(u16 u) {
    union { unsigned int i; float f; } cv; cv.i = ((unsigned int)u) << 16; return cv.f;
}
static __device__ __forceinline__ u16 f2b(float f) {
    union { float f; unsigned int i; } cv; cv.f = f;
    unsigned int x = cv.i;
    return (u16)((x + 0x7fffu + ((x >> 16) & 1u)) >> 16);
}

// ---------------- A2 = -exp(A_log) * log2(e) ----------------
__global__ __launch_bounds__(256) void k_a2(const float* __restrict__ A_log,
                                            float* __restrict__ A2) {
    int i = blockIdx.x * 256 + threadIdx.x;
    A2[i] = -__expf(A_log[i]) * 1.44269504088896340736f;
}

// ---------------- weight transpose f32 (K,N) -> bf16 (N,K) ----------------
__global__ __launch_bounds__(256)
void k_tr(const float* __restrict__ W, u16* __restrict__ Wt, int K, int N) {
    __shared__ float t[64][65];
    const int bk = blockIdx.y << 6, bn = blockIdx.x << 6;
    const int r0 = threadIdx.x >> 4, c0 = (threadIdx.x & 15) << 2;
    #pragma unroll
    for (int i = 0; i < 4; ++i) {
        float4 v = *(const float4*)(W + (size_t)(bk + r0 + i * 16) * N + bn + c0);
        t[r0 + i * 16][c0 + 0] = v.x; t[r0 + i * 16][c0 + 1] = v.y;
        t[r0 + i * 16][c0 + 2] = v.z; t[r0 + i * 16][c0 + 3] = v.w;
    }
    __syncthreads();
    #pragma unroll
    for (int i = 0; i < 4; ++i) {
        const int n = r0 + i * 16;
        ushort4 o;
        o.x = f2b(t[c0 + 0][n]); o.y = f2b(t[c0 + 1][n]);
        o.z = f2b(t[c0 + 2][n]); o.w = f2b(t[c0 + 3][n]);
        *(ushort4*)(Wt + (size_t)(bn + n) * K + bk + c0) = o;
    }
}

// ---------------- pack [W_del|W_B|W_C] -> Wcat (96, 2048) bf16 B^T ----------------
__global__ __launch_bounds__(256)
void k_cat(const float* __restrict__ W_del, const float* __restrict__ W_B,
           const float* __restrict__ W_C, u16* __restrict__ Wcat) {
    const int i = blockIdx.x * 256 + threadIdx.x;   // 96*2048
    const int n = i >> 11, k = i & 2047;
    float v;
    if (n < 64)      v = W_del[(size_t)k * DTRN + n];
    else if (n < 80) v = W_B[(size_t)k * SDIM + (n - 64)];
    else             v = W_C[(size_t)k * SDIM + (n - 80)];
    Wcat[i] = f2b(v);
}

// ---------------- LayerNorm: x (f32) -> xn (bf16) ----------------
__global__ __launch_bounds__(256) void k_ln(const float* __restrict__ x,
                                            const float* __restrict__ g,
                                            const float* __restrict__ bta,
                                            u16* __restrict__ xn) {
    const int row = blockIdx.x, tid = threadIdx.x;
    const float4 xv = ((const float4*)(x + (size_t)row * HIDN))[tid];
    float s  = xv.x + xv.y + xv.z + xv.w;
    float ss = fmaf(xv.x, xv.x, fmaf(xv.y, xv.y, fmaf(xv.z, xv.z, xv.w * xv.w)));
    #pragma unroll
    for (int o = 32; o > 0; o >>= 1) { s += __shfl_down(s, o); ss += __shfl_down(ss, o); }
    __shared__ float as[4], bs[4];
    const int wid = tid >> 6, lane = tid & 63;
    if (lane == 0) { as[wid] = s; bs[wid] = ss; }
    __syncthreads();
    const float S  = as[0] + as[1] + as[2] + as[3];
    const float SS = bs[0] + bs[1] + bs[2] + bs[3];
    const float mean = S * (1.f / HIDN);
    const float var  = SS * (1.f / HIDN) - mean * mean;
    const float r = rsqrtf(var + 1e-5f);
    const float4 gv = ((const float4*)g)[tid];
    const float4 bv = ((const float4*)bta)[tid];
    ushort4 o;
    o.x = f2b((xv.x - mean) * r * gv.x + bv.x);
    o.y = f2b((xv.y - mean) * r * gv.y + bv.y);
    o.z = f2b((xv.z - mean) * r * gv.z + bv.z);
    o.w = f2b((xv.w - mean) * r * gv.w + bv.w);
    ((ushort4*)(xn + (size_t)row * HIDN))[tid] = o;
}

// ---------------- MFMA bf16 GEMM: C = A @ Bt^T (m97 structure) ----------------
#define MEPI_SPLIT_SILU 0
#define MEPI_OUT        1
#define MEPI_SP         2

template<int EPI>
__global__ __launch_bounds__(256)
void mgemm(const u16* __restrict__ A, const u16* __restrict__ Bt,
           const float* __restrict__ bias, void* __restrict__ O0,
           void* __restrict__ O1, const float* __restrict__ res,
           int N, int K) {
    __shared__ u16 As[128 * 32];
    __shared__ u16 Bs[128 * 32];
    const int tid  = threadIdx.x;
    const int wave = tid >> 6, lane = tid & 63;
    const int brow = blockIdx.y * 128, bcol = blockIdx.x * 128;
    const int wm = wave >> 1, wn = wave & 1;
    const int r  = lane & 15, kh = lane >> 4;

    f32x4 acc[4][4];
    #pragma unroll
    for (int m = 0; m < 4; m++)
        #pragma unroll
        for (int n = 0; n < 4; n++) acc[m][n] = (f32x4){0.f, 0.f, 0.f, 0.f};

    const u16* ga0 = A  + (size_t)(brow +      (tid >> 2)) * K + (tid & 3) * 8;
    const u16* ga1 = A  + (size_t)(brow + 64 + (tid >> 2)) * K + (tid & 3) * 8;
    const u16* gb0 = Bt + (size_t)(bcol +      (tid >> 2)) * K + (tid & 3) * 8;
    const u16* gb1 = Bt + (size_t)(bcol + 64 + (tid >> 2)) * K + (tid & 3) * 8;
    u16* lA0 = As + (wave * 64) * 8;
    u16* lA1 = As + (256 + wave * 64) * 8;
    u16* lB0 = Bs + (wave * 64) * 8;
    u16* lB1 = Bs + (256 + wave * 64) * 8;

    for (int k0 = 0; k0 < K; k0 += 32) {
        __syncthreads();
        __builtin_amdgcn_global_load_lds((const __attribute__((address_space(1))) void*)(ga0 + k0),
                                         (__attribute__((address_space(3))) void*)lA0, 16, 0, 0);
        __builtin_amdgcn_global_load_lds((const __attribute__((address_space(1))) void*)(ga1 + k0),
                                         (__attribute__((address_space(3))) void*)lA1, 16, 0, 0);
        __builtin_amdgcn_global_load_lds((const __attribute__((address_space(1))) void*)(gb0 + k0),
                                         (__attribute__((address_space(3))) void*)lB0, 16, 0, 0);
        __builtin_amdgcn_global_load_lds((const __attribute__((address_space(1))) void*)(gb1 + k0),
                                         (__attribute__((address_space(3))) void*)lB1, 16, 0, 0);
        __syncthreads();
        bf16x8 af[4], bfr[4];
        #pragma unroll
        for (int mf = 0; mf < 4; ++mf)
            af[mf] = *(const bf16x8*)(As + ((wm * 64 + mf * 16 + r) * 32 + kh * 8));
        #pragma unroll
        for (int nf = 0; nf < 4; ++nf)
            bfr[nf] = *(const bf16x8*)(Bs + ((wn * 64 + nf * 16 + r) * 32 + kh * 8));
        #pragma unroll
        for (int mf = 0; mf < 4; ++mf)
            #pragma unroll
            for (int nf = 0; nf < 4; ++nf)
                acc[mf][nf] = __builtin_amdgcn_mfma_f32_16x16x32_bf16(af[mf], bfr[nf], acc[mf][nf], 0, 0, 0);
    }

    const int orow = brow + wm * 64 + kh * 4;
    const int ocol = bcol + wn * 64 + r;
    if constexpr (EPI == MEPI_SPLIT_SILU) {
        u16* dst; int cb;
        if (bcol < EXPN) { dst = (u16*)O0; cb = ocol; }
        else             { dst = (u16*)O1; cb = ocol - EXPN; }
        #pragma unroll
        for (int mf = 0; mf < 4; ++mf)
            #pragma unroll
            for (int nf = 0; nf < 4; ++nf)
                #pragma unroll
                for (int j = 0; j < 4; ++j) {
                    const int row = orow + mf * 16 + j;
                    const int col = ocol + nf * 16;
                    float v = acc[mf][nf][j] + bias[col];
                    float sv = v * (1.f / (1.f + __expf(-v)));
                    dst[(size_t)row * EXPN + cb + nf * 16] = f2b(sv);
                }
    } else if constexpr (EPI == MEPI_SP) {
        u16* o = (u16*)O0;
        #pragma unroll
        for (int mf = 0; mf < 4; ++mf)
            #pragma unroll
            for (int nf = 0; nf < 4; ++nf)
                #pragma unroll
                for (int j = 0; j < 4; ++j) {
                    const int row = orow + mf * 16 + j;
                    const int col = ocol + nf * 16;
                    float v = acc[mf][nf][j] + bias[col];
                    float sp = fmaxf(v, 0.f) + log1pf(__expf(-fabsf(v)));
                    o[(size_t)row * N + col] = f2b(sp);
                }
    } else {
        float* o = (float*)O0;
        #pragma unroll
        for (int mf = 0; mf < 4; ++mf)
            #pragma unroll
            for (int nf = 0; nf < 4; ++nf)
                #pragma unroll
                for (int j = 0; j < 4; ++j) {
                    const int row = orow + mf * 16 + j;
                    const int col = ocol + nf * 16;
                    o[(size_t)row * N + col] = acc[mf][nf][j] + bias[col] + res[(size_t)row * N + col];
                }
    }
}

// ---------------- fused split-K projection: P = u @ Wcat^T (M x 96) ----------------
// grid (KSPL, M/128). 4 waves: wave w -> rows w*32..w*32+31, all 96 cols.
__global__ __launch_bounds__(256)
void k_proj(const u16* __restrict__ A, const u16* __restrict__ Wcat,
            float* __restrict__ Ppart) {
    __shared__ u16 As[128 * 32];
    __shared__ u16 Bs[96 * 32];
    const int tid  = threadIdx.x;
    const int wave = tid >> 6, lane = tid & 63;
    const int brow = blockIdx.y * 128;
    const int ks   = blockIdx.x;
    const int r = lane & 15, kh = lane >> 4;

    f32x4 acc[2][6];
    #pragma unroll
    for (int m = 0; m < 2; m++)
        #pragma unroll
        for (int n = 0; n < 6; n++) acc[m][n] = (f32x4){0.f, 0.f, 0.f, 0.f};

    const u16* ga0 = A + (size_t)(brow +      (tid >> 2)) * EXPN + ks * KCH + (tid & 3) * 8;
    const u16* ga1 = A + (size_t)(brow + 64 + (tid >> 2)) * EXPN + ks * KCH + (tid & 3) * 8;
    const u16* gb0 = Wcat + (size_t)(tid >> 2) * EXPN + ks * KCH + (tid & 3) * 8;
    const u16* gb1 = Wcat + (size_t)(64 + (tid >> 2)) * EXPN + ks * KCH + (tid & 3) * 8;  // tid<128
    u16* lA0 = As + (wave * 64) * 8;
    u16* lA1 = As + (256 + wave * 64) * 8;
    u16* lB0 = Bs + (wave * 64) * 8;
    u16* lB1 = Bs + (256 + wave * 64) * 8;   // wave 0,1 only

    for (int k0 = 0; k0 < KCH; k0 += 32) {
        __syncthreads();
        __builtin_amdgcn_global_load_lds((const __attribute__((address_space(1))) void*)(ga0 + k0),
                                         (__attribute__((address_space(3))) void*)lA0, 16, 0, 0);
        __builtin_amdgcn_global_load_lds((const __attribute__((address_space(1))) void*)(ga1 + k0),
                                         (__attribute__((address_space(3))) void*)lA1, 16, 0, 0);
        __builtin_amdgcn_global_load_lds((const __attribute__((address_space(1))) void*)(gb0 + k0),
                                         (__attribute__((address_space(3))) void*)lB0, 16, 0, 0);
        if (tid < 128)
            __builtin_amdgcn_global_load_lds((const __attribute__((address_space(1))) void*)(gb1 + k0),
                                             (__attribute__((address_space(3))) void*)lB1, 16, 0, 0);
        __syncthreads();
        bf16x8 af[2], bfr[6];
        #pragma unroll
        for (int mf = 0; mf < 2; ++mf)
            af[mf] = *(const bf16x8*)(As + ((wave * 32 + mf * 16 + r) * 32 + kh * 8));
        #pragma unroll
        for (int nf = 0; nf < 6; ++nf)
            bfr[nf] = *(const bf16x8*)(Bs + ((nf * 16 + r) * 32 + kh * 8));
        #pragma unroll
        for (int mf = 0; mf < 2; ++mf)
            #pragma unroll
            for (int nf = 0; nf < 6; ++nf)
                acc[mf][nf] = __builtin_amdgcn_mfma_f32_16x16x32_bf16(af[mf], bfr[nf], acc[mf][nf], 0, 0, 0);
    }
    const int orow = brow + wave * 32 + kh * 4;
    #pragma unroll
    for (int mf = 0; mf < 2; ++mf)
        #pragma unroll
        for (int nf = 0; nf < 6; ++nf)
            #pragma unroll
            for (int j = 0; j < 4; ++j)
                Ppart[((size_t)ks * MMN + orow + mf * 16 + j) * 96 + nf * 16 + r] = acc[mf][nf][j];
}

// ---------------- reduce split-K partials -> t1 (bf16), Bm, Cm (f32) ----------------
__global__ __launch_bounds__(192)
void k_red(const float* __restrict__ Ppart, const float* __restrict__ b_del,
           const float* __restrict__ b_B, const float* __restrict__ b_C,
           u16* __restrict__ t1b, float* __restrict__ Bm, float* __restrict__ Cm) {
    const int tid = threadIdx.x;
    const int ri  = tid / 96, col = tid - ri * 96;
    const int row = blockIdx.x * 2 + ri;
    float s = 0.f;
    #pragma unroll
    for (int ks = 0; ks < KSPL; ++ks)
        s += Ppart[((size_t)ks * MMN + row) * 96 + col];
    if (col < 64)      t1b[(size_t)row * DTRN + col] = f2b(s + b_del[col]);
    else if (col < 80) Bm[(size_t)row * SDIM + col - 64] = s + b_B[col - 64];
    else               Cm[(size_t)row * SDIM + col - 80] = s + b_C[col - 80];
}

// ---------------- chunked selective scan ----------------
__global__ __launch_bounds__(256)
void k_scan1(const u16* __restrict__ ub, const u16* __restrict__ db,
             const float* __restrict__ Bm, const float* __restrict__ A2,
             float* __restrict__ hend, float* __restrict__ Pp) {
    const int e = blockIdx.x * 256 + threadIdx.x;
    const int c = blockIdx.y, b = blockIdx.z;
    float a2[SDIM], h[SDIM], P[SDIM];
    {
        const float4* ap = (const float4*)(A2 + (size_t)e * SDIM);
        float4 v0 = ap[0], v1 = ap[1], v2 = ap[2], v3 = ap[3];
        a2[0]=v0.x; a2[1]=v0.y; a2[2]=v0.z; a2[3]=v0.w;
        a2[4]=v1.x; a2[5]=v1.y; a2[6]=v1.z; a2[7]=v1.w;
        a2[8]=v2.x; a2[9]=v2.y; a2[10]=v2.z; a2[11]=v2.w;
        a2[12]=v3.x; a2[13]=v3.y; a2[14]=v3.z; a2[15]=v3.w;
    }
    #pragma unroll
    for (int s = 0; s < SDIM; s++) { h[s] = 0.f; P[s] = 1.f; }
    const int t0 = c * CLEN;
    size_t rb = ((size_t)b * TTN + t0) * EXPN + e;
    size_t bb_ = ((size_t)b * TTN + t0) * SDIM;
    for (int tt = 0; tt < CLEN; ++tt) {
        const float d  = b2f(db[rb]);
        const float uv = b2f(ub[rb]);
        const float4* bp = (const float4*)(Bm + bb_);
        float4 b0 = bp[0], b1 = bp[1], b2v = bp[2], b3 = bp[3];
        float bv[SDIM] = { b0.x,b0.y,b0.z,b0.w, b1.x,b1.y,b1.z,b1.w,
                           b2v.x,b2v.y,b2v.z,b2v.w, b3.x,b3.y,b3.z,b3.w };
        const float du = d * uv;
        #pragma unroll
        for (int s = 0; s < SDIM; ++s) {
            float ad = exp2f(d * a2[s]);
            h[s] = fmaf(ad, h[s], du * bv[s]);
            P[s] *= ad;
        }
        rb += EXPN; bb_ += SDIM;
    }
    size_t ob = ((size_t)(b * NCHUNK + c) * SDIM) * EXPN + e;
    #pragma unroll
    for (int s = 0; s < SDIM; ++s) {
        hend[ob + (size_t)s * EXPN] = h[s];
        Pp  [ob + (size_t)s * EXPN] = P[s];
    }
}

__global__ __launch_bounds__(256)
void k_fix(const float* __restrict__ hend, const float* __restrict__ Pp,
           float* __restrict__ hinit) {
    const int i = blockIdx.x * 256 + threadIdx.x;
    const int b = blockIdx.y;
    float hi = 0.f;
    size_t base = ((size_t)b * NCHUNK) * SDIM * EXPN + i;
    for (int cc = 0; cc < NCHUNK; ++cc) {
        size_t idx = base + (size_t)cc * SDIM * EXPN;
        hinit[idx] = hi;
        hi = fmaf(Pp[idx], hi, hend[idx]);
    }
}

__global__ __launch_bounds__(256)
void k_scan2(const u16* __restrict__ ub, const u16* __restrict__ db,
             const u16* __restrict__ sgb, const float* __restrict__ Bm,
             const float* __restrict__ Cm, const float* __restrict__ A2,
             const float* __restrict__ hinit, const float* __restrict__ Dp,
             u16* __restrict__ yb) {
    const int e = blockIdx.x * 256 + threadIdx.x;
    const int c = blockIdx.y, b = blockIdx.z;
    float a2[SDIM], h[SDIM];
    {
        const float4* ap = (const float4*)(A2 + (size_t)e * SDIM);
        float4 v0 = ap[0], v1 = ap[1], v2 = ap[2], v3 = ap[3];
        a2[0]=v0.x; a2[1]=v0.y; a2[2]=v0.z; a2[3]=v0.w;
        a2[4]=v1.x; a2[5]=v1.y; a2[6]=v1.z; a2[7]=v1.w;
        a2[8]=v2.x; a2[9]=v2.y; a2[10]=v2.z; a2[11]=v2.w;
        a2[12]=v3.x; a2[13]=v3.y; a2[14]=v3.z; a2[15]=v3.w;
    }
    {
        size_t hb = ((size_t)(b * NCHUNK + c) * SDIM) * EXPN + e;
        #pragma unroll
        for (int s = 0; s < SDIM; s++) h[s] = hinit[hb + (size_t)s * EXPN];
    }
    const float dpe = Dp[e];
    const int t0 = c * CLEN;
    size_t rb = ((size_t)b * TTN + t0) * EXPN + e;
    size_t bb_ = ((size_t)b * TTN + t0) * SDIM;
    for (int tt = 0; tt < CLEN; ++tt) {
        const float d   = b2f(db[rb]);
        const float uv  = b2f(ub[rb]);
        const float sgv = b2f(sgb[rb]);
        const float4* bp = (const float4*)(Bm + bb_);
        const float4* cp = (const float4*)(Cm + bb_);
        float4 b0 = bp[0], b1 = bp[1], b2v = bp[2], b3 = bp[3];
        float4 c0 = cp[0], c1 = cp[1], c2v = cp[2], c3 = cp[3];
        float bv[SDIM] = { b0.x,b0.y,b0.z,b0.w, b1.x,b1.y,b1.z,b1.w,
                           b2v.x,b2v.y,b2v.z,b2v.w, b3.x,b3.y,b3.z,b3.w };
        float cv[SDIM] = { c0.x,c0.y,c0.z,c0.w, c1.x,c1.y,c1.z,c1.w,
                           c2v.x,c2v.y,c2v.z,c2v.w, c3.x,c3.y,c3.z,c3.w };
        const float du = d * uv;
        float yt = 0.f;
        #pragma unroll
        for (int s = 0; s < SDIM; ++s) {
            float ad = exp2f(d * a2[s]);
            h[s] = fmaf(ad, h[s], du * bv[s]);
            yt = fmaf(cv[s], h[s], yt);
        }
        yb[rb] = f2b(fmaf(uv, dpe, yt) * sgv);
        rb += EXPN; bb_ += SDIM;
    }
}

// ---------------- launch ----------------
extern "C" void kernel_launch(void* const* d_in, const int* in_sizes, int n_in,
                              void* d_out, int out_size, void* d_ws, size_t ws_size,
                              hipStream_t stream) {
    const float* x     = (const float*)d_in[0];
    const float* ln_g  = (const float*)d_in[1];
    const float* ln_b  = (const float*)d_in[2];
    const float* W_in  = (const float*)d_in[3];
    const float* b_in  = (const float*)d_in[4];
    const float* W_del = (const float*)d_in[5];
    const float* b_del = (const float*)d_in[6];
    const float* W_dt  = (const float*)d_in[7];
    const float* b_dt  = (const float*)d_in[8];
    const float* W_B   = (const float*)d_in[9];
    const float* b_B   = (const float*)d_in[10];
    const float* W_C   = (const float*)d_in[11];
    const float* b_C   = (const float*)d_in[12];
    const float* A_log = (const float*)d_in[13];
    const float* Dp    = (const float*)d_in[14];
    const float* W_out = (const float*)d_in[15];
    const float* b_out = (const float*)d_in[16];
    float* out = (float*)d_out;

    char* p = (char*)d_ws;
    auto alloc = [&](size_t bytes) {
        char* r = p; p += (bytes + 255) & ~(size_t)255; return (void*)r;
    };
    u16* xn   = (u16*)alloc((size_t)MMN * HIDN * 2);
    u16* u    = (u16*)alloc((size_t)MMN * EXPN * 2);
    u16* sg   = (u16*)alloc((size_t)MMN * EXPN * 2);
    u16* dl   = (u16*)alloc((size_t)MMN * EXPN * 2);
    u16* y    = (u16*)alloc((size_t)MMN * EXPN * 2);
    u16* t1b  = (u16*)alloc((size_t)MMN * DTRN * 2);
    float* Bm = (float*)alloc((size_t)MMN * SDIM * 4);
    float* Cm = (float*)alloc((size_t)MMN * SDIM * 4);
    float* A2 = (float*)alloc((size_t)EXPN * SDIM * 4);
    u16* Wt_in  = (u16*)alloc((size_t)(2 * EXPN) * HIDN * 2);
    u16* Wt_out = (u16*)alloc((size_t)HIDN * EXPN * 2);
    u16* Wcat   = (u16*)alloc((size_t)96 * EXPN * 2);
    u16* Wdt_t  = (u16*)alloc((size_t)EXPN * DTRN * 2);
    const size_t hsz = (size_t)BBN * NCHUNK * EXPN * SDIM * 4;
    float* hend  = (float*)alloc(hsz);
    float* Pp    = (float*)alloc(hsz);
    float* hinit = (float*)alloc(hsz);
    // Ppart (25 MB) aliases the scan scratch (50 MB): consumed by k_red before
    // scan1 first writes hend/Pp.
    float* Ppart = hend;

    k_a2<<<dim3(EXPN * SDIM / 256), 256, 0, stream>>>(A_log, A2);
    k_ln<<<dim3(MMN), 256, 0, stream>>>(x, ln_g, ln_b, xn);
    // weight packs
    k_tr<<<dim3(2 * EXPN / 64, HIDN / 64), 256, 0, stream>>>(W_in, Wt_in, HIDN, 2 * EXPN);
    k_tr<<<dim3(HIDN / 64, EXPN / 64), 256, 0, stream>>>(W_out, Wt_out, EXPN, HIDN);
    k_tr<<<dim3(EXPN / 64, DTRN / 64), 256, 0, stream>>>(W_dt, Wdt_t, DTRN, EXPN);
    k_cat<<<dim3(96 * EXPN / 256), 256, 0, stream>>>(W_del, W_B, W_C, Wcat);

    // xp = xn @ W_in + b_in ; u = silu(left), sg = silu(right)   [MFMA]
    mgemm<MEPI_SPLIT_SILU><<<dim3(2 * EXPN / 128, MMN / 128), 256, 0, stream>>>(
        xn, Wt_in, b_in, u, sg, nullptr, 2 * EXPN, HIDN);
    // fused projections: [t1|Bm|Cm] = u @ [W_del|W_B|W_C]   [MFMA split-K]
    k_proj<<<dim3(KSPL, MMN / 128), 256, 0, stream>>>(u, Wcat, Ppart);
    k_red<<<dim3(MMN / 2), 192, 0, stream>>>(Ppart, b_del, b_B, b_C, t1b, Bm, Cm);
    // delta = softplus(t1 @ W_dt + b_dt)   [MFMA]
    mgemm<MEPI_SP><<<dim3(EXPN / 128, MMN / 128), 256, 0, stream>>>(
        t1b, Wdt_t, b_dt, dl, nullptr, nullptr, EXPN, DTRN);
    // chunked selective scan
    k_scan1<<<dim3(EXPN / 256, NCHUNK, BBN), 256, 0, stream>>>(u, dl, Bm, A2, hend, Pp);
    k_fix<<<dim3(SDIM * EXPN / 256, BBN), 256, 0, stream>>>(hend, Pp, hinit);
    k_scan2<<<dim3(EXPN / 256, NCHUNK, BBN), 256, 0, stream>>>(u, dl, sg, Bm, Cm, A2, hinit, Dp, y);
    // out = y @ W_out + b_out + x   [MFMA]
    mgemm<MEPI_OUT><<<dim3(HIDN / 128, MMN / 128), 256, 0, stream>>>(
        y, Wt_out, b_out, out, nullptr, x, HIDN, EXPN);
}

// Round 4
// 420.133 us; speedup vs baseline: 4.3575x; 1.0419x over previous
//
#include <hip/hip_runtime.h>

#define HIDN 1024
#define EXPN 2048
#define SDIM 16
#define DTRN 64
#define BBN  4
#define TTN  2048
#define MMN  (BBN*TTN)        // 8192 rows
#define NCHUNK 32
#define CLEN (TTN/NCHUNK)     // 64
#define KSPL 8                // split-K chunks for k_proj
#define KCH  (EXPN/KSPL)      // 256

typedef unsigned short u16;
typedef __bf16 bf16x8 __attribute__((ext_vector_type(8)));
typedef float f32x4 __attribute__((ext_vector_type(4)));

static __device__ __forceinline__ float b2f(u16 u) {
    union { unsigned int i; float f; } cv; cv.i = ((unsigned int)u) << 16; return cv.f;
}
static __device__ __forceinline__ u16 f2b(float f) {
    union { float f; unsigned int i; } cv; cv.f = f;
    unsigned int x = cv.i;
    return (u16)((x + 0x7fffu + ((x >> 16) & 1u)) >> 16);
}

// ---------------- fused weight prep: 3 transposes + cat + a2, one launch ----
// seg0: W_in  (1024,4096) -> Wt_in  (4096,1024)  : 64x16 tiles = 1024 blocks
// seg1: W_out (2048,1024) -> Wt_out (1024,2048)  : 16x32 tiles =  512 blocks
// seg2: W_dt  (64,2048)   -> Wdt_t  (2048,64)    : 32x1  tiles =   32 blocks
// seg3: Wcat pack  (96*2048/256 = 768 blocks)
// seg4: A2         (128 blocks)
static __device__ __forceinline__
void tr_tile(const float* __restrict__ W, u16* __restrict__ Wt,
             int K, int N, int bk, int bn, float (*t)[65]) {
    const int r0 = threadIdx.x >> 4, c0 = (threadIdx.x & 15) << 2;
    #pragma unroll
    for (int i = 0; i < 4; ++i) {
        float4 v = *(const float4*)(W + (size_t)(bk + r0 + i * 16) * N + bn + c0);
        t[r0 + i * 16][c0 + 0] = v.x; t[r0 + i * 16][c0 + 1] = v.y;
        t[r0 + i * 16][c0 + 2] = v.z; t[r0 + i * 16][c0 + 3] = v.w;
    }
    __syncthreads();
    #pragma unroll
    for (int i = 0; i < 4; ++i) {
        const int n = r0 + i * 16;
        ushort4 o;
        o.x = f2b(t[c0 + 0][n]); o.y = f2b(t[c0 + 1][n]);
        o.z = f2b(t[c0 + 2][n]); o.w = f2b(t[c0 + 3][n]);
        *(ushort4*)(Wt + (size_t)(bn + n) * K + bk + c0) = o;
    }
}

__global__ __launch_bounds__(256)
void k_prep(const float* __restrict__ W_in, const float* __restrict__ W_out,
            const float* __restrict__ W_dt, const float* __restrict__ W_del,
            const float* __restrict__ W_B, const float* __restrict__ W_C,
            const float* __restrict__ A_log,
            u16* __restrict__ Wt_in, u16* __restrict__ Wt_out,
            u16* __restrict__ Wdt_t, u16* __restrict__ Wcat,
            float* __restrict__ A2) {
    __shared__ float t[64][65];
    int blk = blockIdx.x;
    if (blk < 1024) {                       // W_in transpose (nx=64)
        tr_tile(W_in, Wt_in, HIDN, 2 * EXPN, (blk >> 6) << 6, (blk & 63) << 6, t);
        return;
    }
    blk -= 1024;
    if (blk < 512) {                        // W_out transpose (nx=16)
        tr_tile(W_out, Wt_out, EXPN, HIDN, (blk >> 4) << 6, (blk & 15) << 6, t);
        return;
    }
    blk -= 512;
    if (blk < 32) {                         // W_dt transpose (nx=32, ny=1)
        tr_tile(W_dt, Wdt_t, DTRN, EXPN, 0, blk << 6, t);
        return;
    }
    blk -= 32;
    if (blk < 768) {                        // Wcat pack (96 x 2048)
        const int i = blk * 256 + threadIdx.x;
        const int n = i >> 11, k = i & 2047;
        float v;
        if (n < 64)      v = W_del[(size_t)k * DTRN + n];
        else if (n < 80) v = W_B[(size_t)k * SDIM + (n - 64)];
        else             v = W_C[(size_t)k * SDIM + (n - 80)];
        Wcat[i] = f2b(v);
        return;
    }
    blk -= 768;
    {                                       // A2 = -exp(A_log)*log2(e)
        const int i = blk * 256 + threadIdx.x;
        A2[i] = -__expf(A_log[i]) * 1.44269504088896340736f;
    }
}

// ---------------- LayerNorm: x (f32) -> xn (bf16) ----------------
__global__ __launch_bounds__(256) void k_ln(const float* __restrict__ x,
                                            const float* __restrict__ g,
                                            const float* __restrict__ bta,
                                            u16* __restrict__ xn) {
    const int row = blockIdx.x, tid = threadIdx.x;
    const float4 xv = ((const float4*)(x + (size_t)row * HIDN))[tid];
    float s  = xv.x + xv.y + xv.z + xv.w;
    float ss = fmaf(xv.x, xv.x, fmaf(xv.y, xv.y, fmaf(xv.z, xv.z, xv.w * xv.w)));
    #pragma unroll
    for (int o = 32; o > 0; o >>= 1) { s += __shfl_down(s, o); ss += __shfl_down(ss, o); }
    __shared__ float as[4], bs[4];
    const int wid = tid >> 6, lane = tid & 63;
    if (lane == 0) { as[wid] = s; bs[wid] = ss; }
    __syncthreads();
    const float S  = as[0] + as[1] + as[2] + as[3];
    const float SS = bs[0] + bs[1] + bs[2] + bs[3];
    const float mean = S * (1.f / HIDN);
    const float var  = SS * (1.f / HIDN) - mean * mean;
    const float r = rsqrtf(var + 1e-5f);
    const float4 gv = ((const float4*)g)[tid];
    const float4 bv = ((const float4*)bta)[tid];
    ushort4 o;
    o.x = f2b((xv.x - mean) * r * gv.x + bv.x);
    o.y = f2b((xv.y - mean) * r * gv.y + bv.y);
    o.z = f2b((xv.z - mean) * r * gv.z + bv.z);
    o.w = f2b((xv.w - mean) * r * gv.w + bv.w);
    ((ushort4*)(xn + (size_t)row * HIDN))[tid] = o;
}

// ---------------- MFMA bf16 GEMM, BK=64, XCD-swizzled ----------------
// A: (M,K) bf16 row-major; Bt: (N,K) bf16 row-major. 128x128 tile, BK=64,
// LDS [kk][128][32] per matrix (stride 64B -> same 8-way pattern as BK=32).
#define MEPI_SPLIT_SILU 0
#define MEPI_OUT        1
#define MEPI_SP         2

template<int EPI>
__global__ __launch_bounds__(256)
void mgemm(const u16* __restrict__ A, const u16* __restrict__ Bt,
           const float* __restrict__ bias, void* __restrict__ O0,
           void* __restrict__ O1, const float* __restrict__ res,
           int N, int K) {
    __shared__ u16 As[2][128][32];
    __shared__ u16 Bs[2][128][32];
    const int tid  = threadIdx.x;
    const int wave = tid >> 6, lane = tid & 63;
    // bijective XCD swizzle (grids here are all %8 == 0)
    const int nwg  = gridDim.x * gridDim.y;
    const int orig = blockIdx.y * gridDim.x + blockIdx.x;
    const int swz  = (orig & 7) * (nwg >> 3) + (orig >> 3);
    const int bx   = swz % gridDim.x, by = swz / gridDim.x;
    const int brow = by * 128, bcol = bx * 128;
    const int wm = wave >> 1, wn = wave & 1;
    const int r  = lane & 15, kh = lane >> 4;

    f32x4 acc[4][4];
    #pragma unroll
    for (int m = 0; m < 4; m++)
        #pragma unroll
        for (int n = 0; n < 4; n++) acc[m][n] = (f32x4){0.f, 0.f, 0.f, 0.f};

    // staging slot s = j*256+tid covers LDS elems [s*8, s*8+8) of [2][128][32]:
    //   kk = j>>1, row = (j&1)*64 + tid/4, col = (tid&3)*8
    const u16* ga[4]; const u16* gb[4]; u16* la[4]; u16* lb[4];
    #pragma unroll
    for (int j = 0; j < 4; ++j) {
        const int rj = ((j & 1) << 6) + (tid >> 2);
        const int cj = ((j >> 1) << 5) + (tid & 3) * 8;
        ga[j] = A  + (size_t)(brow + rj) * K + cj;
        gb[j] = Bt + (size_t)(bcol + rj) * K + cj;
        la[j] = &As[0][0][0] + (size_t)(j * 256 + wave * 64) * 8;
        lb[j] = &Bs[0][0][0] + (size_t)(j * 256 + wave * 64) * 8;
    }

    for (int k0 = 0; k0 < K; k0 += 64) {
        __syncthreads();  // prior iteration's LDS reads done
        #pragma unroll
        for (int j = 0; j < 4; ++j) {
            __builtin_amdgcn_global_load_lds((const __attribute__((address_space(1))) void*)(ga[j] + k0),
                                             (__attribute__((address_space(3))) void*)la[j], 16, 0, 0);
            __builtin_amdgcn_global_load_lds((const __attribute__((address_space(1))) void*)(gb[j] + k0),
                                             (__attribute__((address_space(3))) void*)lb[j], 16, 0, 0);
        }
        __syncthreads();  // drains vmcnt before barrier
        bf16x8 af[2][4], bfr[2][4];
        #pragma unroll
        for (int kk = 0; kk < 2; ++kk) {
            #pragma unroll
            for (int mf = 0; mf < 4; ++mf)
                af[kk][mf] = *(const bf16x8*)&As[kk][wm * 64 + mf * 16 + r][kh * 8];
            #pragma unroll
            for (int nf = 0; nf < 4; ++nf)
                bfr[kk][nf] = *(const bf16x8*)&Bs[kk][wn * 64 + nf * 16 + r][kh * 8];
        }
        #pragma unroll
        for (int kk = 0; kk < 2; ++kk)
            #pragma unroll
            for (int mf = 0; mf < 4; ++mf)
                #pragma unroll
                for (int nf = 0; nf < 4; ++nf)
                    acc[mf][nf] = __builtin_amdgcn_mfma_f32_16x16x32_bf16(af[kk][mf], bfr[kk][nf], acc[mf][nf], 0, 0, 0);
    }

    const int orow = brow + wm * 64 + kh * 4;
    const int ocol = bcol + wn * 64 + r;
    if constexpr (EPI == MEPI_SPLIT_SILU) {
        u16* dst; int cb;
        if (bcol < EXPN) { dst = (u16*)O0; cb = ocol; }
        else             { dst = (u16*)O1; cb = ocol - EXPN; }
        #pragma unroll
        for (int mf = 0; mf < 4; ++mf)
            #pragma unroll
            for (int nf = 0; nf < 4; ++nf)
                #pragma unroll
                for (int j = 0; j < 4; ++j) {
                    const int row = orow + mf * 16 + j;
                    const int col = ocol + nf * 16;
                    float v = acc[mf][nf][j] + bias[col];
                    float sv = v * (1.f / (1.f + __expf(-v)));
                    dst[(size_t)row * EXPN + cb + nf * 16] = f2b(sv);
                }
    } else if constexpr (EPI == MEPI_SP) {
        u16* o = (u16*)O0;
        #pragma unroll
        for (int mf = 0; mf < 4; ++mf)
            #pragma unroll
            for (int nf = 0; nf < 4; ++nf)
                #pragma unroll
                for (int j = 0; j < 4; ++j) {
                    const int row = orow + mf * 16 + j;
                    const int col = ocol + nf * 16;
                    float v = acc[mf][nf][j] + bias[col];
                    float sp = fmaxf(v, 0.f) + log1pf(__expf(-fabsf(v)));
                    o[(size_t)row * N + col] = f2b(sp);
                }
    } else {
        float* o = (float*)O0;
        #pragma unroll
        for (int mf = 0; mf < 4; ++mf)
            #pragma unroll
            for (int nf = 0; nf < 4; ++nf)
                #pragma unroll
                for (int j = 0; j < 4; ++j) {
                    const int row = orow + mf * 16 + j;
                    const int col = ocol + nf * 16;
                    o[(size_t)row * N + col] = acc[mf][nf][j] + bias[col] + res[(size_t)row * N + col];
                }
    }
}

// ---------------- fused split-K projection: P = u @ Wcat^T (M x 96) ----------------
__global__ __launch_bounds__(256)
void k_proj(const u16* __restrict__ A, const u16* __restrict__ Wcat,
            float* __restrict__ Ppart) {
    __shared__ u16 As[128 * 32];
    __shared__ u16 Bs[96 * 32];
    const int tid  = threadIdx.x;
    const int wave = tid >> 6, lane = tid & 63;
    const int brow = blockIdx.y * 128;
    const int ks   = blockIdx.x;
    const int r = lane & 15, kh = lane >> 4;

    f32x4 acc[2][6];
    #pragma unroll
    for (int m = 0; m < 2; m++)
        #pragma unroll
        for (int n = 0; n < 6; n++) acc[m][n] = (f32x4){0.f, 0.f, 0.f, 0.f};

    const u16* ga0 = A + (size_t)(brow +      (tid >> 2)) * EXPN + ks * KCH + (tid & 3) * 8;
    const u16* ga1 = A + (size_t)(brow + 64 + (tid >> 2)) * EXPN + ks * KCH + (tid & 3) * 8;
    const u16* gb0 = Wcat + (size_t)(tid >> 2) * EXPN + ks * KCH + (tid & 3) * 8;
    const u16* gb1 = Wcat + (size_t)(64 + (tid >> 2)) * EXPN + ks * KCH + (tid & 3) * 8;
    u16* lA0 = As + (wave * 64) * 8;
    u16* lA1 = As + (256 + wave * 64) * 8;
    u16* lB0 = Bs + (wave * 64) * 8;
    u16* lB1 = Bs + (256 + wave * 64) * 8;

    for (int k0 = 0; k0 < KCH; k0 += 32) {
        __syncthreads();
        __builtin_amdgcn_global_load_lds((const __attribute__((address_space(1))) void*)(ga0 + k0),
                                         (__attribute__((address_space(3))) void*)lA0, 16, 0, 0);
        __builtin_amdgcn_global_load_lds((const __attribute__((address_space(1))) void*)(ga1 + k0),
                                         (__attribute__((address_space(3))) void*)lA1, 16, 0, 0);
        __builtin_amdgcn_global_load_lds((const __attribute__((address_space(1))) void*)(gb0 + k0),
                                         (__attribute__((address_space(3))) void*)lB0, 16, 0, 0);
        if (tid < 128)
            __builtin_amdgcn_global_load_lds((const __attribute__((address_space(1))) void*)(gb1 + k0),
                                             (__attribute__((address_space(3))) void*)lB1, 16, 0, 0);
        __syncthreads();
        bf16x8 af[2], bfr[6];
        #pragma unroll
        for (int mf = 0; mf < 2; ++mf)
            af[mf] = *(const bf16x8*)(As + ((wave * 32 + mf * 16 + r) * 32 + kh * 8));
        #pragma unroll
        for (int nf = 0; nf < 6; ++nf)
            bfr[nf] = *(const bf16x8*)(Bs + ((nf * 16 + r) * 32 + kh * 8));
        #pragma unroll
        for (int mf = 0; mf < 2; ++mf)
            #pragma unroll
            for (int nf = 0; nf < 6; ++nf)
                acc[mf][nf] = __builtin_amdgcn_mfma_f32_16x16x32_bf16(af[mf], bfr[nf], acc[mf][nf], 0, 0, 0);
    }
    const int orow = brow + wave * 32 + kh * 4;
    #pragma unroll
    for (int mf = 0; mf < 2; ++mf)
        #pragma unroll
        for (int nf = 0; nf < 6; ++nf)
            #pragma unroll
            for (int j = 0; j < 4; ++j)
                Ppart[((size_t)ks * MMN + orow + mf * 16 + j) * 96 + nf * 16 + r] = acc[mf][nf][j];
}

// ---------------- reduce split-K partials -> t1 (bf16), Bm, Cm (f32) ----------------
__global__ __launch_bounds__(192)
void k_red(const float* __restrict__ Ppart, const float* __restrict__ b_del,
           const float* __restrict__ b_B, const float* __restrict__ b_C,
           u16* __restrict__ t1b, float* __restrict__ Bm, float* __restrict__ Cm) {
    const int tid = threadIdx.x;
    const int ri  = tid / 96, col = tid - ri * 96;
    const int row = blockIdx.x * 2 + ri;
    float s = 0.f;
    #pragma unroll
    for (int ks = 0; ks < KSPL; ++ks)
        s += Ppart[((size_t)ks * MMN + row) * 96 + col];
    if (col < 64)      t1b[(size_t)row * DTRN + col] = f2b(s + b_del[col]);
    else if (col < 80) Bm[(size_t)row * SDIM + col - 64] = s + b_B[col - 64];
    else               Cm[(size_t)row * SDIM + col - 80] = s + b_C[col - 80];
}

// ---------------- chunked selective scan ----------------
__global__ __launch_bounds__(256)
void k_scan1(const u16* __restrict__ ub, const u16* __restrict__ db,
             const float* __restrict__ Bm, const float* __restrict__ A2,
             float* __restrict__ hend, float* __restrict__ Pp) {
    const int e = blockIdx.x * 256 + threadIdx.x;
    const int c = blockIdx.y, b = blockIdx.z;
    float a2[SDIM], h[SDIM];
    {
        const float4* ap = (const float4*)(A2 + (size_t)e * SDIM);
        float4 v0 = ap[0], v1 = ap[1], v2 = ap[2], v3 = ap[3];
        a2[0]=v0.x; a2[1]=v0.y; a2[2]=v0.z; a2[3]=v0.w;
        a2[4]=v1.x; a2[5]=v1.y; a2[6]=v1.z; a2[7]=v1.w;
        a2[8]=v2.x; a2[9]=v2.y; a2[10]=v2.z; a2[11]=v2.w;
        a2[12]=v3.x; a2[13]=v3.y; a2[14]=v3.z; a2[15]=v3.w;
    }
    #pragma unroll
    for (int s = 0; s < SDIM; s++) h[s] = 0.f;
    float sumd = 0.f;
    const int t0 = c * CLEN;
    size_t rb = ((size_t)b * TTN + t0) * EXPN + e;
    size_t bb_ = ((size_t)b * TTN + t0) * SDIM;
    for (int tt = 0; tt < CLEN; ++tt) {
        const float d  = b2f(db[rb]);
        const float uv = b2f(ub[rb]);
        const float4* bp = (const float4*)(Bm + bb_);
        float4 b0 = bp[0], b1 = bp[1], b2v = bp[2], b3 = bp[3];
        float bv[SDIM] = { b0.x,b0.y,b0.z,b0.w, b1.x,b1.y,b1.z,b1.w,
                           b2v.x,b2v.y,b2v.z,b2v.w, b3.x,b3.y,b3.z,b3.w };
        const float du = d * uv;
        sumd += d;
        #pragma unroll
        for (int s = 0; s < SDIM; ++s) {
            float ad = exp2f(d * a2[s]);
            h[s] = fmaf(ad, h[s], du * bv[s]);
        }
        rb += EXPN; bb_ += SDIM;
    }
    size_t ob = ((size_t)(b * NCHUNK + c) * SDIM) * EXPN + e;
    #pragma unroll
    for (int s = 0; s < SDIM; ++s) {
        hend[ob + (size_t)s * EXPN] = h[s];
        Pp  [ob + (size_t)s * EXPN] = exp2f(a2[s] * sumd);   // prod_t exp2(d_t*a2)
    }
}

__global__ __launch_bounds__(256)
void k_fix(const float* __restrict__ hend, const float* __restrict__ Pp,
           float* __restrict__ hinit) {
    const int i = blockIdx.x * 256 + threadIdx.x;
    const int b = blockIdx.y;
    float hi = 0.f;
    size_t base = ((size_t)b * NCHUNK) * SDIM * EXPN + i;
    for (int cc = 0; cc < NCHUNK; ++cc) {
        size_t idx = base + (size_t)cc * SDIM * EXPN;
        hinit[idx] = hi;
        hi = fmaf(Pp[idx], hi, hend[idx]);
    }
}

__global__ __launch_bounds__(256)
void k_scan2(const u16* __restrict__ ub, const u16* __restrict__ db,
             const u16* __restrict__ sgb, const float* __restrict__ Bm,
             const float* __restrict__ Cm, const float* __restrict__ A2,
             const float* __restrict__ hinit, const float* __restrict__ Dp,
             u16* __restrict__ yb) {
    const int e = blockIdx.x * 256 + threadIdx.x;
    const int c = blockIdx.y, b = blockIdx.z;
    float a2[SDIM], h[SDIM];
    {
        const float4* ap = (const float4*)(A2 + (size_t)e * SDIM);
        float4 v0 = ap[0], v1 = ap[1], v2 = ap[2], v3 = ap[3];
        a2[0]=v0.x; a2[1]=v0.y; a2[2]=v0.z; a2[3]=v0.w;
        a2[4]=v1.x; a2[5]=v1.y; a2[6]=v1.z; a2[7]=v1.w;
        a2[8]=v2.x; a2[9]=v2.y; a2[10]=v2.z; a2[11]=v2.w;
        a2[12]=v3.x; a2[13]=v3.y; a2[14]=v3.z; a2[15]=v3.w;
    }
    {
        size_t hb = ((size_t)(b * NCHUNK + c) * SDIM) * EXPN + e;
        #pragma unroll
        for (int s = 0; s < SDIM; s++) h[s] = hinit[hb + (size_t)s * EXPN];
    }
    const float dpe = Dp[e];
    const int t0 = c * CLEN;
    size_t rb = ((size_t)b * TTN + t0) * EXPN + e;
    size_t bb_ = ((size_t)b * TTN + t0) * SDIM;
    for (int tt = 0; tt < CLEN; ++tt) {
        const float d   = b2f(db[rb]);
        const float uv  = b2f(ub[rb]);
        const float sgv = b2f(sgb[rb]);
        const float4* bp = (const float4*)(Bm + bb_);
        const float4* cp = (const float4*)(Cm + bb_);
        float4 b0 = bp[0], b1 = bp[1], b2v = bp[2], b3 = bp[3];
        float4 c0 = cp[0], c1 = cp[1], c2v = cp[2], c3 = cp[3];
        float bv[SDIM] = { b0.x,b0.y,b0.z,b0.w, b1.x,b1.y,b1.z,b1.w,
                           b2v.x,b2v.y,b2v.z,b2v.w, b3.x,b3.y,b3.z,b3.w };
        float cv[SDIM] = { c0.x,c0.y,c0.z,c0.w, c1.x,c1.y,c1.z,c1.w,
                           c2v.x,c2v.y,c2v.z,c2v.w, c3.x,c3.y,c3.z,c3.w };
        const float du = d * uv;
        float yt = 0.f;
        #pragma unroll
        for (int s = 0; s < SDIM; ++s) {
            float ad = exp2f(d * a2[s]);
            h[s] = fmaf(ad, h[s], du * bv[s]);
            yt = fmaf(cv[s], h[s], yt);
        }
        yb[rb] = f2b(fmaf(uv, dpe, yt) * sgv);
        rb += EXPN; bb_ += SDIM;
    }
}

// ---------------- launch ----------------
extern "C" void kernel_launch(void* const* d_in, const int* in_sizes, int n_in,
                              void* d_out, int out_size, void* d_ws, size_t ws_size,
                              hipStream_t stream) {
    const float* x     = (const float*)d_in[0];
    const float* ln_g  = (const float*)d_in[1];
    const float* ln_b  = (const float*)d_in[2];
    const float* W_in  = (const float*)d_in[3];
    const float* b_in  = (const float*)d_in[4];
    const float* W_del = (const float*)d_in[5];
    const float* b_del = (const float*)d_in[6];
    const float* W_dt  = (const float*)d_in[7];
    const float* b_dt  = (const float*)d_in[8];
    const float* W_B   = (const float*)d_in[9];
    const float* b_B   = (const float*)d_in[10];
    const float* W_C   = (const float*)d_in[11];
    const float* b_C   = (const float*)d_in[12];
    const float* A_log = (const float*)d_in[13];
    const float* Dp    = (const float*)d_in[14];
    const float* W_out = (const float*)d_in[15];
    const float* b_out = (const float*)d_in[16];
    float* out = (float*)d_out;

    char* p = (char*)d_ws;
    auto alloc = [&](size_t bytes) {
        char* r = p; p += (bytes + 255) & ~(size_t)255; return (void*)r;
    };
    u16* xn   = (u16*)alloc((size_t)MMN * HIDN * 2);
    u16* u    = (u16*)alloc((size_t)MMN * EXPN * 2);
    u16* sg   = (u16*)alloc((size_t)MMN * EXPN * 2);
    u16* dl   = (u16*)alloc((size_t)MMN * EXPN * 2);
    u16* y    = (u16*)alloc((size_t)MMN * EXPN * 2);
    u16* t1b  = (u16*)alloc((size_t)MMN * DTRN * 2);
    float* Bm = (float*)alloc((size_t)MMN * SDIM * 4);
    float* Cm = (float*)alloc((size_t)MMN * SDIM * 4);
    float* A2 = (float*)alloc((size_t)EXPN * SDIM * 4);
    u16* Wt_in  = (u16*)alloc((size_t)(2 * EXPN) * HIDN * 2);
    u16* Wt_out = (u16*)alloc((size_t)HIDN * EXPN * 2);
    u16* Wcat   = (u16*)alloc((size_t)96 * EXPN * 2);
    u16* Wdt_t  = (u16*)alloc((size_t)EXPN * DTRN * 2);
    const size_t hsz = (size_t)BBN * NCHUNK * EXPN * SDIM * 4;
    float* hend  = (float*)alloc(hsz);
    float* Pp    = (float*)alloc(hsz);
    float* hinit = (float*)alloc(hsz);
    float* Ppart = hend;   // aliased: consumed by k_red before scan1 writes

    // fused weight prep (transposes + cat + a2), one launch
    k_prep<<<dim3(1024 + 512 + 32 + 768 + 128), 256, 0, stream>>>(
        W_in, W_out, W_dt, W_del, W_B, W_C, A_log, Wt_in, Wt_out, Wdt_t, Wcat, A2);
    k_ln<<<dim3(MMN), 256, 0, stream>>>(x, ln_g, ln_b, xn);

    // xp = xn @ W_in + b_in ; u = silu(left), sg = silu(right)   [MFMA BK=64]
    mgemm<MEPI_SPLIT_SILU><<<dim3(2 * EXPN / 128, MMN / 128), 256, 0, stream>>>(
        xn, Wt_in, b_in, u, sg, nullptr, 2 * EXPN, HIDN);
    // fused projections: [t1|Bm|Cm] = u @ [W_del|W_B|W_C]   [MFMA split-K]
    k_proj<<<dim3(KSPL, MMN / 128), 256, 0, stream>>>(u, Wcat, Ppart);
    k_red<<<dim3(MMN / 2), 192, 0, stream>>>(Ppart, b_del, b_B, b_C, t1b, Bm, Cm);
    // delta = softplus(t1 @ W_dt + b_dt)   [MFMA BK=64, single K-step]
    mgemm<MEPI_SP><<<dim3(EXPN / 128, MMN / 128), 256, 0, stream>>>(
        t1b, Wdt_t, b_dt, dl, nullptr, nullptr, EXPN, DTRN);
    // chunked selective scan
    k_scan1<<<dim3(EXPN / 256, NCHUNK, BBN), 256, 0, stream>>>(u, dl, Bm, A2, hend, Pp);
    k_fix<<<dim3(SDIM * EXPN / 256, BBN), 256, 0, stream>>>(hend, Pp, hinit);
    k_scan2<<<dim3(EXPN / 256, NCHUNK, BBN), 256, 0, stream>>>(u, dl, sg, Bm, Cm, A2, hinit, Dp, y);
    // out = y @ W_out + b_out + x   [MFMA BK=64]
    mgemm<MEPI_OUT><<<dim3(HIDN / 128, MMN / 128), 256, 0, stream>>>(
        y, Wt_out, b_out, out, nullptr, x, HIDN, EXPN);
}

// Round 5
// 412.441 us; speedup vs baseline: 4.4388x; 1.0186x over previous
//
#include <hip/hip_runtime.h>

#define HIDN 1024
#define EXPN 2048
#define SDIM 16
#define DTRN 64
#define BBN  4
#define TTN  2048
#define MMN  (BBN*TTN)        // 8192 rows
#define NCHUNK 32
#define CLEN (TTN/NCHUNK)     // 64
#define KSPL 8                // split-K chunks for k_proj
#define KCH  (EXPN/KSPL)      // 256

typedef unsigned short u16;
typedef __bf16 bf16x8 __attribute__((ext_vector_type(8)));
typedef float f32x4 __attribute__((ext_vector_type(4)));

static __device__ __forceinline__ float b2f(u16 u) {
    union { unsigned int i; float f; } cv; cv.i = ((unsigned int)u) << 16; return cv.f;
}
static __device__ __forceinline__ u16 f2b(float f) {
    union { float f; unsigned int i; } cv; cv.f = f;
    unsigned int x = cv.i;
    return (u16)((x + 0x7fffu + ((x >> 16) & 1u)) >> 16);
}

// ---------------- fused weight prep: 3 transposes + cat + a2, one launch ----
static __device__ __forceinline__
void tr_tile(const float* __restrict__ W, u16* __restrict__ Wt,
             int K, int N, int bk, int bn, float (*t)[65]) {
    const int r0 = threadIdx.x >> 4, c0 = (threadIdx.x & 15) << 2;
    #pragma unroll
    for (int i = 0; i < 4; ++i) {
        float4 v = *(const float4*)(W + (size_t)(bk + r0 + i * 16) * N + bn + c0);
        t[r0 + i * 16][c0 + 0] = v.x; t[r0 + i * 16][c0 + 1] = v.y;
        t[r0 + i * 16][c0 + 2] = v.z; t[r0 + i * 16][c0 + 3] = v.w;
    }
    __syncthreads();
    #pragma unroll
    for (int i = 0; i < 4; ++i) {
        const int n = r0 + i * 16;
        ushort4 o;
        o.x = f2b(t[c0 + 0][n]); o.y = f2b(t[c0 + 1][n]);
        o.z = f2b(t[c0 + 2][n]); o.w = f2b(t[c0 + 3][n]);
        *(ushort4*)(Wt + (size_t)(bn + n) * K + bk + c0) = o;
    }
}

__global__ __launch_bounds__(256)
void k_prep(const float* __restrict__ W_in, const float* __restrict__ W_out,
            const float* __restrict__ W_dt, const float* __restrict__ W_del,
            const float* __restrict__ W_B, const float* __restrict__ W_C,
            const float* __restrict__ A_log,
            u16* __restrict__ Wt_in, u16* __restrict__ Wt_out,
            u16* __restrict__ Wdt_t, u16* __restrict__ Wcat,
            float* __restrict__ A2) {
    __shared__ float t[64][65];
    int blk = blockIdx.x;
    if (blk < 1024) {
        tr_tile(W_in, Wt_in, HIDN, 2 * EXPN, (blk >> 6) << 6, (blk & 63) << 6, t);
        return;
    }
    blk -= 1024;
    if (blk < 512) {
        tr_tile(W_out, Wt_out, EXPN, HIDN, (blk >> 4) << 6, (blk & 15) << 6, t);
        return;
    }
    blk -= 512;
    if (blk < 32) {
        tr_tile(W_dt, Wdt_t, DTRN, EXPN, 0, blk << 6, t);
        return;
    }
    blk -= 32;
    if (blk < 768) {
        const int i = blk * 256 + threadIdx.x;
        const int n = i >> 11, k = i & 2047;
        float v;
        if (n < 64)      v = W_del[(size_t)k * DTRN + n];
        else if (n < 80) v = W_B[(size_t)k * SDIM + (n - 64)];
        else             v = W_C[(size_t)k * SDIM + (n - 80)];
        Wcat[i] = f2b(v);
        return;
    }
    blk -= 768;
    {
        const int i = blk * 256 + threadIdx.x;
        A2[i] = -__expf(A_log[i]) * 1.44269504088896340736f;
    }
}

// ---------------- LayerNorm: x (f32) -> xn (bf16) ----------------
__global__ __launch_bounds__(256) void k_ln(const float* __restrict__ x,
                                            const float* __restrict__ g,
                                            const float* __restrict__ bta,
                                            u16* __restrict__ xn) {
    const int row = blockIdx.x, tid = threadIdx.x;
    const float4 xv = ((const float4*)(x + (size_t)row * HIDN))[tid];
    float s  = xv.x + xv.y + xv.z + xv.w;
    float ss = fmaf(xv.x, xv.x, fmaf(xv.y, xv.y, fmaf(xv.z, xv.z, xv.w * xv.w)));
    #pragma unroll
    for (int o = 32; o > 0; o >>= 1) { s += __shfl_down(s, o); ss += __shfl_down(ss, o); }
    __shared__ float as[4], bs[4];
    const int wid = tid >> 6, lane = tid & 63;
    if (lane == 0) { as[wid] = s; bs[wid] = ss; }
    __syncthreads();
    const float S  = as[0] + as[1] + as[2] + as[3];
    const float SS = bs[0] + bs[1] + bs[2] + bs[3];
    const float mean = S * (1.f / HIDN);
    const float var  = SS * (1.f / HIDN) - mean * mean;
    const float r = rsqrtf(var + 1e-5f);
    const float4 gv = ((const float4*)g)[tid];
    const float4 bv = ((const float4*)bta)[tid];
    ushort4 o;
    o.x = f2b((xv.x - mean) * r * gv.x + bv.x);
    o.y = f2b((xv.y - mean) * r * gv.y + bv.y);
    o.z = f2b((xv.z - mean) * r * gv.z + bv.z);
    o.w = f2b((xv.w - mean) * r * gv.w + bv.w);
    ((ushort4*)(xn + (size_t)row * HIDN))[tid] = o;
}

// ============ 256x256 8-phase MFMA GEMM (T2+T3+T4+T5), C = A @ Bt^T =========
// 512 threads = 8 waves (2M x 4N); BK=64; LDS 128 KiB = 2 K-tile buffers of
// 4 segs (A0,A1,B0,B1) x 16 KiB. Seg layout: subtiled [16][2][16][32] with
// st_16x32 XOR swizzle (byte ^= ((byte>>9)&1)<<5  ==  col ^= 16 when r16>=8).
// Staging: linear global_load_lds dest + inverse-swizzled global source.
#define MEPI_SPLIT_SILU 0
#define MEPI_OUT        1
#define MEPI_SP         2

static __device__ __forceinline__
void stage256(const u16* __restrict__ A, const u16* __restrict__ Bt,
              u16 (*seg)[8192], int brow, int bcol, int K, int k0,
              const int* srow, const int* scol, int tid) {
    #pragma unroll
    for (int j = 0; j < 2; ++j) {
        #pragma unroll
        for (int h = 0; h < 2; ++h) {
            const u16* sa = A + (size_t)(brow + h * 128 + srow[j]) * K + k0 + scol[j];
            __builtin_amdgcn_global_load_lds(
                (const __attribute__((address_space(1))) void*)sa,
                (__attribute__((address_space(3))) void*)&seg[h][(j * 512 + tid) * 8], 16, 0, 0);
            const u16* sb = Bt + (size_t)(bcol + h * 128 + srow[j]) * K + k0 + scol[j];
            __builtin_amdgcn_global_load_lds(
                (const __attribute__((address_space(1))) void*)sb,
                (__attribute__((address_space(3))) void*)&seg[2 + h][(j * 512 + tid) * 8], 16, 0, 0);
        }
    }
}

template<int EPI>
__global__ __launch_bounds__(512, 2)
void mgemm256(const u16* __restrict__ A, const u16* __restrict__ Bt,
              const float* __restrict__ bias, void* __restrict__ O0,
              void* __restrict__ O1, const float* __restrict__ res,
              int N, int K) {
    __shared__ u16 lds[2][4][8192];
    const int tid  = threadIdx.x;
    const int lane = tid & 63, wid = tid >> 6;
    const int wm = wid >> 2, wn = wid & 3;       // 2 x 4 waves
    const int r  = lane & 15, kh = lane >> 4;
    const int brow = blockIdx.y * 256, bcol = blockIdx.x * 256;

    // per-thread staging source coords: LDS chunk q = j*512+tid holds global
    // (row, col^swz) so that swizzled reads see natural data.
    int srow[2], scol[2];
    #pragma unroll
    for (int j = 0; j < 2; ++j) {
        const int q = j * 512 + tid;
        const int sub = q >> 6, qi = q & 63;
        const int qis = qi ^ (((qi >> 5) & 1) << 1);
        srow[j] = (sub >> 1) * 16 + (qi >> 2);
        scol[j] = ((sub & 1) << 5) + (qis & 3) * 8;
    }
    const int swz_kh = kh ^ (((r >> 3) & 1) << 1);
    const int rbase  = r * 32 + swz_kh * 8;      // u16 index within a sub-slab
    const int bq     = wn & 1;                   // B row-block within its half

    f32x4 acc[8][4];
    #pragma unroll
    for (int i = 0; i < 8; ++i)
        #pragma unroll
        for (int n = 0; n < 4; ++n) acc[i][n] = (f32x4){0.f, 0.f, 0.f, 0.f};

    const int NT = K >> 6;                       // >= 2
    stage256(A, Bt, lds[0], brow, bcol, K, 0, srow, scol, tid);
    stage256(A, Bt, lds[1], brow, bcol, K, 64, srow, scol, tid);
    asm volatile("s_waitcnt vmcnt(8)" ::: "memory");   // tile0 landed
    __builtin_amdgcn_s_barrier();
    asm volatile("" ::: "memory");

    bf16x8 a[4][2], b[2][2][2];
    for (int kt = 0; kt < NT; ++kt) {
        const u16* segA = lds[kt & 1][wm];
        const u16* segB = lds[kt & 1][2 + (wn >> 1)];
        // ---- phase 1: load a(mh0) + b(nh0); MFMA quadrant (mh0,nh0)
        #pragma unroll
        for (int mf = 0; mf < 4; ++mf)
            #pragma unroll
            for (int kk = 0; kk < 2; ++kk)
                a[mf][kk] = *(const bf16x8*)&segA[(mf * 2 + kk) * 512 + rbase];
        #pragma unroll
        for (int nf = 0; nf < 2; ++nf)
            #pragma unroll
            for (int kk = 0; kk < 2; ++kk)
                b[0][nf][kk] = *(const bf16x8*)&segB[((bq * 4 + nf) * 2 + kk) * 512 + rbase];
        __builtin_amdgcn_s_barrier(); asm volatile("" ::: "memory");
        __builtin_amdgcn_s_setprio(1);
        #pragma unroll
        for (int mf = 0; mf < 4; ++mf)
            #pragma unroll
            for (int nf = 0; nf < 2; ++nf)
                #pragma unroll
                for (int kk = 0; kk < 2; ++kk)
                    acc[mf][nf] = __builtin_amdgcn_mfma_f32_16x16x32_bf16(a[mf][kk], b[0][nf][kk], acc[mf][nf], 0, 0, 0);
        __builtin_amdgcn_s_setprio(0);
        __builtin_amdgcn_s_barrier(); asm volatile("" ::: "memory");
        // ---- phase 2: load b(nh1); MFMA (mh0,nh1)
        #pragma unroll
        for (int nf = 0; nf < 2; ++nf)
            #pragma unroll
            for (int kk = 0; kk < 2; ++kk)
                b[1][nf][kk] = *(const bf16x8*)&segB[((bq * 4 + 2 + nf) * 2 + kk) * 512 + rbase];
        __builtin_amdgcn_s_barrier(); asm volatile("" ::: "memory");
        __builtin_amdgcn_s_setprio(1);
        #pragma unroll
        for (int mf = 0; mf < 4; ++mf)
            #pragma unroll
            for (int nf = 0; nf < 2; ++nf)
                #pragma unroll
                for (int kk = 0; kk < 2; ++kk)
                    acc[mf][2 + nf] = __builtin_amdgcn_mfma_f32_16x16x32_bf16(a[mf][kk], b[1][nf][kk], acc[mf][2 + nf], 0, 0, 0);
        __builtin_amdgcn_s_setprio(0);
        __builtin_amdgcn_s_barrier(); asm volatile("" ::: "memory");
        // ---- phase 3: load a(mh1); MFMA (mh1,nh0)
        #pragma unroll
        for (int mf = 0; mf < 4; ++mf)
            #pragma unroll
            for (int kk = 0; kk < 2; ++kk)
                a[mf][kk] = *(const bf16x8*)&segA[((4 + mf) * 2 + kk) * 512 + rbase];
        __builtin_amdgcn_s_barrier(); asm volatile("" ::: "memory");
        __builtin_amdgcn_s_setprio(1);
        #pragma unroll
        for (int mf = 0; mf < 4; ++mf)
            #pragma unroll
            for (int nf = 0; nf < 2; ++nf)
                #pragma unroll
                for (int kk = 0; kk < 2; ++kk)
                    acc[4 + mf][nf] = __builtin_amdgcn_mfma_f32_16x16x32_bf16(a[mf][kk], b[0][nf][kk], acc[4 + mf][nf], 0, 0, 0);
        __builtin_amdgcn_s_setprio(0);
        __builtin_amdgcn_s_barrier(); asm volatile("" ::: "memory");
        // ---- phase 4: stage kt+2 into this buffer (reads done); MFMA (mh1,nh1);
        //      counted vmcnt (never 0 mid-loop): prev tile's 8 loads landed.
        if (kt + 2 < NT)
            stage256(A, Bt, lds[kt & 1], brow, bcol, K, (kt + 2) * 64, srow, scol, tid);
        __builtin_amdgcn_s_setprio(1);
        #pragma unroll
        for (int mf = 0; mf < 4; ++mf)
            #pragma unroll
            for (int nf = 0; nf < 2; ++nf)
                #pragma unroll
                for (int kk = 0; kk < 2; ++kk)
                    acc[4 + mf][2 + nf] = __builtin_amdgcn_mfma_f32_16x16x32_bf16(a[mf][kk], b[1][nf][kk], acc[4 + mf][2 + nf], 0, 0, 0);
        __builtin_amdgcn_s_setprio(0);
        if (kt + 2 < NT) { asm volatile("s_waitcnt vmcnt(8)" ::: "memory"); }
        else             { asm volatile("s_waitcnt vmcnt(0)" ::: "memory"); }
        __builtin_amdgcn_s_barrier(); asm volatile("" ::: "memory");
    }

    // epilogue: C row = brow + wm*128 + Mf*16 + kh*4 + j ; col = bcol + wn*64 + Nf*16 + r
    const int orow = brow + wm * 128 + kh * 4;
    const int ocol = bcol + wn * 64 + r;
    if constexpr (EPI == MEPI_SPLIT_SILU) {
        u16* dst; int cb;
        if (bcol < EXPN) { dst = (u16*)O0; cb = ocol; }
        else             { dst = (u16*)O1; cb = ocol - EXPN; }
        #pragma unroll
        for (int Mf = 0; Mf < 8; ++Mf)
            #pragma unroll
            for (int Nf = 0; Nf < 4; ++Nf)
                #pragma unroll
                for (int j = 0; j < 4; ++j) {
                    const int row = orow + Mf * 16 + j;
                    const int col = ocol + Nf * 16;
                    float v = acc[Mf][Nf][j] + bias[col];
                    float sv = v * (1.f / (1.f + __expf(-v)));
                    dst[(size_t)row * EXPN + cb + Nf * 16] = f2b(sv);
                }
    } else {
        float* o = (float*)O0;
        #pragma unroll
        for (int Mf = 0; Mf < 8; ++Mf)
            #pragma unroll
            for (int Nf = 0; Nf < 4; ++Nf)
                #pragma unroll
                for (int j = 0; j < 4; ++j) {
                    const int row = orow + Mf * 16 + j;
                    const int col = ocol + Nf * 16;
                    o[(size_t)row * N + col] = acc[Mf][Nf][j] + bias[col] + res[(size_t)row * N + col];
                }
    }
}

// ---------------- 128x128 MFMA GEMM (m97 structure, BK=32) ----------------
template<int EPI>
__global__ __launch_bounds__(256)
void mgemm(const u16* __restrict__ A, const u16* __restrict__ Bt,
           const float* __restrict__ bias, void* __restrict__ O0,
           void* __restrict__ O1, const float* __restrict__ res,
           int N, int K) {
    __shared__ u16 As[128 * 32];
    __shared__ u16 Bs[128 * 32];
    const int tid  = threadIdx.x;
    const int wave = tid >> 6, lane = tid & 63;
    const int brow = blockIdx.y * 128, bcol = blockIdx.x * 128;
    const int wm = wave >> 1, wn = wave & 1;
    const int r  = lane & 15, kh = lane >> 4;

    f32x4 acc[4][4];
    #pragma unroll
    for (int m = 0; m < 4; m++)
        #pragma unroll
        for (int n = 0; n < 4; n++) acc[m][n] = (f32x4){0.f, 0.f, 0.f, 0.f};

    const u16* ga0 = A  + (size_t)(brow +      (tid >> 2)) * K + (tid & 3) * 8;
    const u16* ga1 = A  + (size_t)(brow + 64 + (tid >> 2)) * K + (tid & 3) * 8;
    const u16* gb0 = Bt + (size_t)(bcol +      (tid >> 2)) * K + (tid & 3) * 8;
    const u16* gb1 = Bt + (size_t)(bcol + 64 + (tid >> 2)) * K + (tid & 3) * 8;
    u16* lA0 = As + (wave * 64) * 8;
    u16* lA1 = As + (256 + wave * 64) * 8;
    u16* lB0 = Bs + (wave * 64) * 8;
    u16* lB1 = Bs + (256 + wave * 64) * 8;

    for (int k0 = 0; k0 < K; k0 += 32) {
        __syncthreads();
        __builtin_amdgcn_global_load_lds((const __attribute__((address_space(1))) void*)(ga0 + k0),
                                         (__attribute__((address_space(3))) void*)lA0, 16, 0, 0);
        __builtin_amdgcn_global_load_lds((const __attribute__((address_space(1))) void*)(ga1 + k0),
                                         (__attribute__((address_space(3))) void*)lA1, 16, 0, 0);
        __builtin_amdgcn_global_load_lds((const __attribute__((address_space(1))) void*)(gb0 + k0),
                                         (__attribute__((address_space(3))) void*)lB0, 16, 0, 0);
        __builtin_amdgcn_global_load_lds((const __attribute__((address_space(1))) void*)(gb1 + k0),
                                         (__attribute__((address_space(3))) void*)lB1, 16, 0, 0);
        __syncthreads();
        bf16x8 af[4], bfr[4];
        #pragma unroll
        for (int mf = 0; mf < 4; ++mf)
            af[mf] = *(const bf16x8*)(As + ((wm * 64 + mf * 16 + r) * 32 + kh * 8));
        #pragma unroll
        for (int nf = 0; nf < 4; ++nf)
            bfr[nf] = *(const bf16x8*)(Bs + ((wn * 64 + nf * 16 + r) * 32 + kh * 8));
        #pragma unroll
        for (int mf = 0; mf < 4; ++mf)
            #pragma unroll
            for (int nf = 0; nf < 4; ++nf)
                acc[mf][nf] = __builtin_amdgcn_mfma_f32_16x16x32_bf16(af[mf], bfr[nf], acc[mf][nf], 0, 0, 0);
    }

    const int orow = brow + wm * 64 + kh * 4;
    const int ocol = bcol + wn * 64 + r;
    if constexpr (EPI == MEPI_SPLIT_SILU) {
        u16* dst; int cb;
        if (bcol < EXPN) { dst = (u16*)O0; cb = ocol; }
        else             { dst = (u16*)O1; cb = ocol - EXPN; }
        #pragma unroll
        for (int mf = 0; mf < 4; ++mf)
            #pragma unroll
            for (int nf = 0; nf < 4; ++nf)
                #pragma unroll
                for (int j = 0; j < 4; ++j) {
                    const int row = orow + mf * 16 + j;
                    const int col = ocol + nf * 16;
                    float v = acc[mf][nf][j] + bias[col];
                    float sv = v * (1.f / (1.f + __expf(-v)));
                    dst[(size_t)row * EXPN + cb + nf * 16] = f2b(sv);
                }
    } else if constexpr (EPI == MEPI_SP) {
        u16* o = (u16*)O0;
        #pragma unroll
        for (int mf = 0; mf < 4; ++mf)
            #pragma unroll
            for (int nf = 0; nf < 4; ++nf)
                #pragma unroll
                for (int j = 0; j < 4; ++j) {
                    const int row = orow + mf * 16 + j;
                    const int col = ocol + nf * 16;
                    float v = acc[mf][nf][j] + bias[col];
                    float sp = fmaxf(v, 0.f) + log1pf(__expf(-fabsf(v)));
                    o[(size_t)row * N + col] = f2b(sp);
                }
    } else {
        float* o = (float*)O0;
        #pragma unroll
        for (int mf = 0; mf < 4; ++mf)
            #pragma unroll
            for (int nf = 0; nf < 4; ++nf)
                #pragma unroll
                for (int j = 0; j < 4; ++j) {
                    const int row = orow + mf * 16 + j;
                    const int col = ocol + nf * 16;
                    o[(size_t)row * N + col] = acc[mf][nf][j] + bias[col] + res[(size_t)row * N + col];
                }
    }
}

// ---------------- fused split-K projection: P = u @ Wcat^T (M x 96) ----------------
__global__ __launch_bounds__(256)
void k_proj(const u16* __restrict__ A, const u16* __restrict__ Wcat,
            float* __restrict__ Ppart) {
    __shared__ u16 As[128 * 32];
    __shared__ u16 Bs[96 * 32];
    const int tid  = threadIdx.x;
    const int wave = tid >> 6, lane = tid & 63;
    const int brow = blockIdx.y * 128;
    const int ks   = blockIdx.x;
    const int r = lane & 15, kh = lane >> 4;

    f32x4 acc[2][6];
    #pragma unroll
    for (int m = 0; m < 2; m++)
        #pragma unroll
        for (int n = 0; n < 6; n++) acc[m][n] = (f32x4){0.f, 0.f, 0.f, 0.f};

    const u16* ga0 = A + (size_t)(brow +      (tid >> 2)) * EXPN + ks * KCH + (tid & 3) * 8;
    const u16* ga1 = A + (size_t)(brow + 64 + (tid >> 2)) * EXPN + ks * KCH + (tid & 3) * 8;
    const u16* gb0 = Wcat + (size_t)(tid >> 2) * EXPN + ks * KCH + (tid & 3) * 8;
    const u16* gb1 = Wcat + (size_t)(64 + (tid >> 2)) * EXPN + ks * KCH + (tid & 3) * 8;
    u16* lA0 = As + (wave * 64) * 8;
    u16* lA1 = As + (256 + wave * 64) * 8;
    u16* lB0 = Bs + (wave * 64) * 8;
    u16* lB1 = Bs + (256 + wave * 64) * 8;

    for (int k0 = 0; k0 < KCH; k0 += 32) {
        __syncthreads();
        __builtin_amdgcn_global_load_lds((const __attribute__((address_space(1))) void*)(ga0 + k0),
                                         (__attribute__((address_space(3))) void*)lA0, 16, 0, 0);
        __builtin_amdgcn_global_load_lds((const __attribute__((address_space(1))) void*)(ga1 + k0),
                                         (__attribute__((address_space(3))) void*)lA1, 16, 0, 0);
        __builtin_amdgcn_global_load_lds((const __attribute__((address_space(1))) void*)(gb0 + k0),
                                         (__attribute__((address_space(3))) void*)lB0, 16, 0, 0);
        if (tid < 128)
            __builtin_amdgcn_global_load_lds((const __attribute__((address_space(1))) void*)(gb1 + k0),
                                             (__attribute__((address_space(3))) void*)lB1, 16, 0, 0);
        __syncthreads();
        bf16x8 af[2], bfr[6];
        #pragma unroll
        for (int mf = 0; mf < 2; ++mf)
            af[mf] = *(const bf16x8*)(As + ((wave * 32 + mf * 16 + r) * 32 + kh * 8));
        #pragma unroll
        for (int nf = 0; nf < 6; ++nf)
            bfr[nf] = *(const bf16x8*)(Bs + ((nf * 16 + r) * 32 + kh * 8));
        #pragma unroll
        for (int mf = 0; mf < 2; ++mf)
            #pragma unroll
            for (int nf = 0; nf < 6; ++nf)
                acc[mf][nf] = __builtin_amdgcn_mfma_f32_16x16x32_bf16(af[mf], bfr[nf], acc[mf][nf], 0, 0, 0);
    }
    const int orow = brow + wave * 32 + kh * 4;
    #pragma unroll
    for (int mf = 0; mf < 2; ++mf)
        #pragma unroll
        for (int nf = 0; nf < 6; ++nf)
            #pragma unroll
            for (int j = 0; j < 4; ++j)
                Ppart[((size_t)ks * MMN + orow + mf * 16 + j) * 96 + nf * 16 + r] = acc[mf][nf][j];
}

// ---------------- reduce split-K partials -> t1 (bf16), Bm, Cm (f32) ----------------
__global__ __launch_bounds__(192)
void k_red(const float* __restrict__ Ppart, const float* __restrict__ b_del,
           const float* __restrict__ b_B, const float* __restrict__ b_C,
           u16* __restrict__ t1b, float* __restrict__ Bm, float* __restrict__ Cm) {
    const int tid = threadIdx.x;
    const int ri  = tid / 96, col = tid - ri * 96;
    const int row = blockIdx.x * 2 + ri;
    float s = 0.f;
    #pragma unroll
    for (int ks = 0; ks < KSPL; ++ks)
        s += Ppart[((size_t)ks * MMN + row) * 96 + col];
    if (col < 64)      t1b[(size_t)row * DTRN + col] = f2b(s + b_del[col]);
    else if (col < 80) Bm[(size_t)row * SDIM + col - 64] = s + b_B[col - 64];
    else               Cm[(size_t)row * SDIM + col - 80] = s + b_C[col - 80];
}

// ---------------- chunked selective scan ----------------
__global__ __launch_bounds__(256)
void k_scan1(const u16* __restrict__ ub, const u16* __restrict__ db,
             const float* __restrict__ Bm, const float* __restrict__ A2,
             float* __restrict__ hend, float* __restrict__ Pp) {
    const int e = blockIdx.x * 256 + threadIdx.x;
    const int c = blockIdx.y, b = blockIdx.z;
    float a2[SDIM], h[SDIM];
    {
        const float4* ap = (const float4*)(A2 + (size_t)e * SDIM);
        float4 v0 = ap[0], v1 = ap[1], v2 = ap[2], v3 = ap[3];
        a2[0]=v0.x; a2[1]=v0.y; a2[2]=v0.z; a2[3]=v0.w;
        a2[4]=v1.x; a2[5]=v1.y; a2[6]=v1.z; a2[7]=v1.w;
        a2[8]=v2.x; a2[9]=v2.y; a2[10]=v2.z; a2[11]=v2.w;
        a2[12]=v3.x; a2[13]=v3.y; a2[14]=v3.z; a2[15]=v3.w;
    }
    #pragma unroll
    for (int s = 0; s < SDIM; s++) h[s] = 0.f;
    float sumd = 0.f;
    const int t0 = c * CLEN;
    size_t rb = ((size_t)b * TTN + t0) * EXPN + e;
    size_t bb_ = ((size_t)b * TTN + t0) * SDIM;
    for (int tt = 0; tt < CLEN; ++tt) {
        const float d  = b2f(db[rb]);
        const float uv = b2f(ub[rb]);
        const float4* bp = (const float4*)(Bm + bb_);
        float4 b0 = bp[0], b1 = bp[1], b2v = bp[2], b3 = bp[3];
        float bv[SDIM] = { b0.x,b0.y,b0.z,b0.w, b1.x,b1.y,b1.z,b1.w,
                           b2v.x,b2v.y,b2v.z,b2v.w, b3.x,b3.y,b3.z,b3.w };
        const float du = d * uv;
        sumd += d;
        #pragma unroll
        for (int s = 0; s < SDIM; ++s) {
            float ad = exp2f(d * a2[s]);
            h[s] = fmaf(ad, h[s], du * bv[s]);
        }
        rb += EXPN; bb_ += SDIM;
    }
    size_t ob = ((size_t)(b * NCHUNK + c) * SDIM) * EXPN + e;
    #pragma unroll
    for (int s = 0; s < SDIM; ++s) {
        hend[ob + (size_t)s * EXPN] = h[s];
        Pp  [ob + (size_t)s * EXPN] = exp2f(a2[s] * sumd);
    }
}

__global__ __launch_bounds__(256)
void k_fix(const float* __restrict__ hend, const float* __restrict__ Pp,
           float* __restrict__ hinit) {
    const int i = blockIdx.x * 256 + threadIdx.x;
    const int b = blockIdx.y;
    float hi = 0.f;
    size_t base = ((size_t)b * NCHUNK) * SDIM * EXPN + i;
    for (int cc = 0; cc < NCHUNK; ++cc) {
        size_t idx = base + (size_t)cc * SDIM * EXPN;
        hinit[idx] = hi;
        hi = fmaf(Pp[idx], hi, hend[idx]);
    }
}

__global__ __launch_bounds__(256)
void k_scan2(const u16* __restrict__ ub, const u16* __restrict__ db,
             const u16* __restrict__ sgb, const float* __restrict__ Bm,
             const float* __restrict__ Cm, const float* __restrict__ A2,
             const float* __restrict__ hinit, const float* __restrict__ Dp,
             u16* __restrict__ yb) {
    const int e = blockIdx.x * 256 + threadIdx.x;
    const int c = blockIdx.y, b = blockIdx.z;
    float a2[SDIM], h[SDIM];
    {
        const float4* ap = (const float4*)(A2 + (size_t)e * SDIM);
        float4 v0 = ap[0], v1 = ap[1], v2 = ap[2], v3 = ap[3];
        a2[0]=v0.x; a2[1]=v0.y; a2[2]=v0.z; a2[3]=v0.w;
        a2[4]=v1.x; a2[5]=v1.y; a2[6]=v1.z; a2[7]=v1.w;
        a2[8]=v2.x; a2[9]=v2.y; a2[10]=v2.z; a2[11]=v2.w;
        a2[12]=v3.x; a2[13]=v3.y; a2[14]=v3.z; a2[15]=v3.w;
    }
    {
        size_t hb = ((size_t)(b * NCHUNK + c) * SDIM) * EXPN + e;
        #pragma unroll
        for (int s = 0; s < SDIM; s++) h[s] = hinit[hb + (size_t)s * EXPN];
    }
    const float dpe = Dp[e];
    const int t0 = c * CLEN;
    size_t rb = ((size_t)b * TTN + t0) * EXPN + e;
    size_t bb_ = ((size_t)b * TTN + t0) * SDIM;
    for (int tt = 0; tt < CLEN; ++tt) {
        const float d   = b2f(db[rb]);
        const float uv  = b2f(ub[rb]);
        const float sgv = b2f(sgb[rb]);
        const float4* bp = (const float4*)(Bm + bb_);
        const float4* cp = (const float4*)(Cm + bb_);
        float4 b0 = bp[0], b1 = bp[1], b2v = bp[2], b3 = bp[3];
        float4 c0 = cp[0], c1 = cp[1], c2v = cp[2], c3 = cp[3];
        float bv[SDIM] = { b0.x,b0.y,b0.z,b0.w, b1.x,b1.y,b1.z,b1.w,
                           b2v.x,b2v.y,b2v.z,b2v.w, b3.x,b3.y,b3.z,b3.w };
        float cv[SDIM] = { c0.x,c0.y,c0.z,c0.w, c1.x,c1.y,c1.z,c1.w,
                           c2v.x,c2v.y,c2v.z,c2v.w, c3.x,c3.y,c3.z,c3.w };
        const float du = d * uv;
        float yt = 0.f;
        #pragma unroll
        for (int s = 0; s < SDIM; ++s) {
            float ad = exp2f(d * a2[s]);
            h[s] = fmaf(ad, h[s], du * bv[s]);
            yt = fmaf(cv[s], h[s], yt);
        }
        yb[rb] = f2b(fmaf(uv, dpe, yt) * sgv);
        rb += EXPN; bb_ += SDIM;
    }
}

// ---------------- launch ----------------
extern "C" void kernel_launch(void* const* d_in, const int* in_sizes, int n_in,
                              void* d_out, int out_size, void* d_ws, size_t ws_size,
                              hipStream_t stream) {
    const float* x     = (const float*)d_in[0];
    const float* ln_g  = (const float*)d_in[1];
    const float* ln_b  = (const float*)d_in[2];
    const float* W_in  = (const float*)d_in[3];
    const float* b_in  = (const float*)d_in[4];
    const float* W_del = (const float*)d_in[5];
    const float* b_del = (const float*)d_in[6];
    const float* W_dt  = (const float*)d_in[7];
    const float* b_dt  = (const float*)d_in[8];
    const float* W_B   = (const float*)d_in[9];
    const float* b_B   = (const float*)d_in[10];
    const float* W_C   = (const float*)d_in[11];
    const float* b_C   = (const float*)d_in[12];
    const float* A_log = (const float*)d_in[13];
    const float* Dp    = (const float*)d_in[14];
    const float* W_out = (const float*)d_in[15];
    const float* b_out = (const float*)d_in[16];
    float* out = (float*)d_out;

    char* p = (char*)d_ws;
    auto alloc = [&](size_t bytes) {
        char* r = p; p += (bytes + 255) & ~(size_t)255; return (void*)r;
    };
    u16* xn   = (u16*)alloc((size_t)MMN * HIDN * 2);
    u16* u    = (u16*)alloc((size_t)MMN * EXPN * 2);
    u16* sg   = (u16*)alloc((size_t)MMN * EXPN * 2);
    u16* dl   = (u16*)alloc((size_t)MMN * EXPN * 2);
    u16* y    = (u16*)alloc((size_t)MMN * EXPN * 2);
    u16* t1b  = (u16*)alloc((size_t)MMN * DTRN * 2);
    float* Bm = (float*)alloc((size_t)MMN * SDIM * 4);
    float* Cm = (float*)alloc((size_t)MMN * SDIM * 4);
    float* A2 = (float*)alloc((size_t)EXPN * SDIM * 4);
    u16* Wt_in  = (u16*)alloc((size_t)(2 * EXPN) * HIDN * 2);
    u16* Wt_out = (u16*)alloc((size_t)HIDN * EXPN * 2);
    u16* Wcat   = (u16*)alloc((size_t)96 * EXPN * 2);
    u16* Wdt_t  = (u16*)alloc((size_t)EXPN * DTRN * 2);
    const size_t hsz = (size_t)BBN * NCHUNK * EXPN * SDIM * 4;
    float* hend  = (float*)alloc(hsz);
    float* Pp    = (float*)alloc(hsz);
    float* hinit = (float*)alloc(hsz);
    float* Ppart = hend;   // aliased: consumed by k_red before scan1 writes

    k_prep<<<dim3(1024 + 512 + 32 + 768 + 128), 256, 0, stream>>>(
        W_in, W_out, W_dt, W_del, W_B, W_C, A_log, Wt_in, Wt_out, Wdt_t, Wcat, A2);
    k_ln<<<dim3(MMN), 256, 0, stream>>>(x, ln_g, ln_b, xn);

    // xp = xn @ W_in + b_in ; u = silu(left), sg = silu(right)  [256^2 8-phase]
    mgemm256<MEPI_SPLIT_SILU><<<dim3(2 * EXPN / 256, MMN / 256), 512, 0, stream>>>(
        xn, Wt_in, b_in, u, sg, nullptr, 2 * EXPN, HIDN);
    // fused projections: [t1|Bm|Cm] = u @ [W_del|W_B|W_C]   [MFMA split-K]
    k_proj<<<dim3(KSPL, MMN / 128), 256, 0, stream>>>(u, Wcat, Ppart);
    k_red<<<dim3(MMN / 2), 192, 0, stream>>>(Ppart, b_del, b_B, b_C, t1b, Bm, Cm);
    // delta = softplus(t1 @ W_dt + b_dt)   [MFMA 128^2]
    mgemm<MEPI_SP><<<dim3(EXPN / 128, MMN / 128), 256, 0, stream>>>(
        t1b, Wdt_t, b_dt, dl, nullptr, nullptr, EXPN, DTRN);
    // chunked selective scan
    k_scan1<<<dim3(EXPN / 256, NCHUNK, BBN), 256, 0, stream>>>(u, dl, Bm, A2, hend, Pp);
    k_fix<<<dim3(SDIM * EXPN / 256, BBN), 256, 0, stream>>>(hend, Pp, hinit);
    k_scan2<<<dim3(EXPN / 256, NCHUNK, BBN), 256, 0, stream>>>(u, dl, sg, Bm, Cm, A2, hinit, Dp, y);
    // out = y @ W_out + b_out + x   [MFMA 128^2]
    mgemm<MEPI_OUT><<<dim3(HIDN / 128, MMN / 128), 256, 0, stream>>>(
        y, Wt_out, b_out, out, nullptr, x, HIDN, EXPN);
}

// Round 6
// 307.144 us; speedup vs baseline: 5.9605x; 1.3428x over previous
//
#include <hip/hip_runtime.h>

#define HIDN 1024
#define EXPN 2048
#define SDIM 16
#define DTRN 64
#define BBN  4
#define TTN  2048
#define MMN  (BBN*TTN)        // 8192 rows
#define NCHUNK 32
#define CLEN (TTN/NCHUNK)     // 64
#define KSPL 8                // split-K chunks for k_proj
#define KCH  (EXPN/KSPL)      // 256

typedef unsigned short u16;
typedef __bf16 bf16x8 __attribute__((ext_vector_type(8)));
typedef float f32x4 __attribute__((ext_vector_type(4)));

static __device__ __forceinline__ float b2f(u16 u) {
    union { unsigned int i; float f; } cv; cv.i = ((unsigned int)u) << 16; return cv.f;
}
static __device__ __forceinline__ u16 f2b(float f) {
    union { float f; unsigned int i; } cv; cv.f = f;
    unsigned int x = cv.i;
    return (u16)((x + 0x7fffu + ((x >> 16) & 1u)) >> 16);
}
// single v_exp_f32 (trans pipe); args here are small => no denormal concerns
static __device__ __forceinline__ float fexp2(float x) {
    return __builtin_amdgcn_exp2f(x);
}

// ---------------- fused weight prep: 3 transposes + cat + a2, one launch ----
static __device__ __forceinline__
void tr_tile(const float* __restrict__ W, u16* __restrict__ Wt,
             int K, int N, int bk, int bn, float (*t)[65]) {
    const int r0 = threadIdx.x >> 4, c0 = (threadIdx.x & 15) << 2;
    #pragma unroll
    for (int i = 0; i < 4; ++i) {
        float4 v = *(const float4*)(W + (size_t)(bk + r0 + i * 16) * N + bn + c0);
        t[r0 + i * 16][c0 + 0] = v.x; t[r0 + i * 16][c0 + 1] = v.y;
        t[r0 + i * 16][c0 + 2] = v.z; t[r0 + i * 16][c0 + 3] = v.w;
    }
    __syncthreads();
    #pragma unroll
    for (int i = 0; i < 4; ++i) {
        const int n = r0 + i * 16;
        ushort4 o;
        o.x = f2b(t[c0 + 0][n]); o.y = f2b(t[c0 + 1][n]);
        o.z = f2b(t[c0 + 2][n]); o.w = f2b(t[c0 + 3][n]);
        *(ushort4*)(Wt + (size_t)(bn + n) * K + bk + c0) = o;
    }
}

__global__ __launch_bounds__(256)
void k_prep(const float* __restrict__ W_in, const float* __restrict__ W_out,
            const float* __restrict__ W_dt, const float* __restrict__ W_del,
            const float* __restrict__ W_B, const float* __restrict__ W_C,
            const float* __restrict__ A_log,
            u16* __restrict__ Wt_in, u16* __restrict__ Wt_out,
            u16* __restrict__ Wdt_t, u16* __restrict__ Wcat,
            float* __restrict__ A2) {
    __shared__ float t[64][65];
    int blk = blockIdx.x;
    if (blk < 1024) {
        tr_tile(W_in, Wt_in, HIDN, 2 * EXPN, (blk >> 6) << 6, (blk & 63) << 6, t);
        return;
    }
    blk -= 1024;
    if (blk < 512) {
        tr_tile(W_out, Wt_out, EXPN, HIDN, (blk >> 4) << 6, (blk & 15) << 6, t);
        return;
    }
    blk -= 512;
    if (blk < 32) {
        tr_tile(W_dt, Wdt_t, DTRN, EXPN, 0, blk << 6, t);
        return;
    }
    blk -= 32;
    if (blk < 768) {
        const int i = blk * 256 + threadIdx.x;
        const int n = i >> 11, k = i & 2047;
        float v;
        if (n < 64)      v = W_del[(size_t)k * DTRN + n];
        else if (n < 80) v = W_B[(size_t)k * SDIM + (n - 64)];
        else             v = W_C[(size_t)k * SDIM + (n - 80)];
        Wcat[i] = f2b(v);
        return;
    }
    blk -= 768;
    {
        const int i = blk * 256 + threadIdx.x;
        A2[i] = -__expf(A_log[i]) * 1.44269504088896340736f;
    }
}

// ---------------- LayerNorm: x (f32) -> xn (bf16) ----------------
__global__ __launch_bounds__(256) void k_ln(const float* __restrict__ x,
                                            const float* __restrict__ g,
                                            const float* __restrict__ bta,
                                            u16* __restrict__ xn) {
    const int row = blockIdx.x, tid = threadIdx.x;
    const float4 xv = ((const float4*)(x + (size_t)row * HIDN))[tid];
    float s  = xv.x + xv.y + xv.z + xv.w;
    float ss = fmaf(xv.x, xv.x, fmaf(xv.y, xv.y, fmaf(xv.z, xv.z, xv.w * xv.w)));
    #pragma unroll
    for (int o = 32; o > 0; o >>= 1) { s += __shfl_down(s, o); ss += __shfl_down(ss, o); }
    __shared__ float as[4], bs[4];
    const int wid = tid >> 6, lane = tid & 63;
    if (lane == 0) { as[wid] = s; bs[wid] = ss; }
    __syncthreads();
    const float S  = as[0] + as[1] + as[2] + as[3];
    const float SS = bs[0] + bs[1] + bs[2] + bs[3];
    const float mean = S * (1.f / HIDN);
    const float var  = SS * (1.f / HIDN) - mean * mean;
    const float r = rsqrtf(var + 1e-5f);
    const float4 gv = ((const float4*)g)[tid];
    const float4 bv = ((const float4*)bta)[tid];
    ushort4 o;
    o.x = f2b((xv.x - mean) * r * gv.x + bv.x);
    o.y = f2b((xv.y - mean) * r * gv.y + bv.y);
    o.z = f2b((xv.z - mean) * r * gv.z + bv.z);
    o.w = f2b((xv.w - mean) * r * gv.w + bv.w);
    ((ushort4*)(xn + (size_t)row * HIDN))[tid] = o;
}

// ============ 256x256 8-phase MFMA GEMM (T2+T3+T4+T5), C = A @ Bt^T =========
#define MEPI_SPLIT_SILU 0
#define MEPI_OUT        1
#define MEPI_SP         2

static __device__ __forceinline__
void stage256(const u16* __restrict__ A, const u16* __restrict__ Bt,
              u16 (*seg)[8192], int brow, int bcol, int K, int k0,
              const int* srow, const int* scol, int tid) {
    #pragma unroll
    for (int j = 0; j < 2; ++j) {
        #pragma unroll
        for (int h = 0; h < 2; ++h) {
            const u16* sa = A + (size_t)(brow + h * 128 + srow[j]) * K + k0 + scol[j];
            __builtin_amdgcn_global_load_lds(
                (const __attribute__((address_space(1))) void*)sa,
                (__attribute__((address_space(3))) void*)&seg[h][(j * 512 + tid) * 8], 16, 0, 0);
            const u16* sb = Bt + (size_t)(bcol + h * 128 + srow[j]) * K + k0 + scol[j];
            __builtin_amdgcn_global_load_lds(
                (const __attribute__((address_space(1))) void*)sb,
                (__attribute__((address_space(3))) void*)&seg[2 + h][(j * 512 + tid) * 8], 16, 0, 0);
        }
    }
}

template<int EPI>
__global__ __launch_bounds__(512, 2)
void mgemm256(const u16* __restrict__ A, const u16* __restrict__ Bt,
              const float* __restrict__ bias, void* __restrict__ O0,
              void* __restrict__ O1, const float* __restrict__ res,
              int N, int K) {
    __shared__ u16 lds[2][4][8192];
    const int tid  = threadIdx.x;
    const int lane = tid & 63, wid = tid >> 6;
    const int wm = wid >> 2, wn = wid & 3;       // 2 x 4 waves
    const int r  = lane & 15, kh = lane >> 4;
    const int brow = blockIdx.y * 256, bcol = blockIdx.x * 256;

    int srow[2], scol[2];
    #pragma unroll
    for (int j = 0; j < 2; ++j) {
        const int q = j * 512 + tid;
        const int sub = q >> 6, qi = q & 63;
        const int qis = qi ^ (((qi >> 5) & 1) << 1);
        srow[j] = (sub >> 1) * 16 + (qi >> 2);
        scol[j] = ((sub & 1) << 5) + (qis & 3) * 8;
    }
    const int swz_kh = kh ^ (((r >> 3) & 1) << 1);
    const int rbase  = r * 32 + swz_kh * 8;
    const int bq     = wn & 1;

    f32x4 acc[8][4];
    #pragma unroll
    for (int i = 0; i < 8; ++i)
        #pragma unroll
        for (int n = 0; n < 4; ++n) acc[i][n] = (f32x4){0.f, 0.f, 0.f, 0.f};

    const int NT = K >> 6;
    stage256(A, Bt, lds[0], brow, bcol, K, 0, srow, scol, tid);
    stage256(A, Bt, lds[1], brow, bcol, K, 64, srow, scol, tid);
    asm volatile("s_waitcnt vmcnt(8)" ::: "memory");
    __builtin_amdgcn_s_barrier();
    asm volatile("" ::: "memory");

    bf16x8 a[4][2], b[2][2][2];
    for (int kt = 0; kt < NT; ++kt) {
        const u16* segA = lds[kt & 1][wm];
        const u16* segB = lds[kt & 1][2 + (wn >> 1)];
        // ---- phase 1
        #pragma unroll
        for (int mf = 0; mf < 4; ++mf)
            #pragma unroll
            for (int kk = 0; kk < 2; ++kk)
                a[mf][kk] = *(const bf16x8*)&segA[(mf * 2 + kk) * 512 + rbase];
        #pragma unroll
        for (int nf = 0; nf < 2; ++nf)
            #pragma unroll
            for (int kk = 0; kk < 2; ++kk)
                b[0][nf][kk] = *(const bf16x8*)&segB[((bq * 4 + nf) * 2 + kk) * 512 + rbase];
        __builtin_amdgcn_s_barrier(); asm volatile("" ::: "memory");
        __builtin_amdgcn_s_setprio(1);
        #pragma unroll
        for (int mf = 0; mf < 4; ++mf)
            #pragma unroll
            for (int nf = 0; nf < 2; ++nf)
                #pragma unroll
                for (int kk = 0; kk < 2; ++kk)
                    acc[mf][nf] = __builtin_amdgcn_mfma_f32_16x16x32_bf16(a[mf][kk], b[0][nf][kk], acc[mf][nf], 0, 0, 0);
        __builtin_amdgcn_s_setprio(0);
        __builtin_amdgcn_s_barrier(); asm volatile("" ::: "memory");
        // ---- phase 2
        #pragma unroll
        for (int nf = 0; nf < 2; ++nf)
            #pragma unroll
            for (int kk = 0; kk < 2; ++kk)
                b[1][nf][kk] = *(const bf16x8*)&segB[((bq * 4 + 2 + nf) * 2 + kk) * 512 + rbase];
        __builtin_amdgcn_s_barrier(); asm volatile("" ::: "memory");
        __builtin_amdgcn_s_setprio(1);
        #pragma unroll
        for (int mf = 0; mf < 4; ++mf)
            #pragma unroll
            for (int nf = 0; nf < 2; ++nf)
                #pragma unroll
                for (int kk = 0; kk < 2; ++kk)
                    acc[mf][2 + nf] = __builtin_amdgcn_mfma_f32_16x16x32_bf16(a[mf][kk], b[1][nf][kk], acc[mf][2 + nf], 0, 0, 0);
        __builtin_amdgcn_s_setprio(0);
        __builtin_amdgcn_s_barrier(); asm volatile("" ::: "memory");
        // ---- phase 3
        #pragma unroll
        for (int mf = 0; mf < 4; ++mf)
            #pragma unroll
            for (int kk = 0; kk < 2; ++kk)
                a[mf][kk] = *(const bf16x8*)&segA[((4 + mf) * 2 + kk) * 512 + rbase];
        __builtin_amdgcn_s_barrier(); asm volatile("" ::: "memory");
        __builtin_amdgcn_s_setprio(1);
        #pragma unroll
        for (int mf = 0; mf < 4; ++mf)
            #pragma unroll
            for (int nf = 0; nf < 2; ++nf)
                #pragma unroll
                for (int kk = 0; kk < 2; ++kk)
                    acc[4 + mf][nf] = __builtin_amdgcn_mfma_f32_16x16x32_bf16(a[mf][kk], b[0][nf][kk], acc[4 + mf][nf], 0, 0, 0);
        __builtin_amdgcn_s_setprio(0);
        __builtin_amdgcn_s_barrier(); asm volatile("" ::: "memory");
        // ---- phase 4: prefetch kt+2; counted vmcnt
        if (kt + 2 < NT)
            stage256(A, Bt, lds[kt & 1], brow, bcol, K, (kt + 2) * 64, srow, scol, tid);
        __builtin_amdgcn_s_setprio(1);
        #pragma unroll
        for (int mf = 0; mf < 4; ++mf)
            #pragma unroll
            for (int nf = 0; nf < 2; ++nf)
                #pragma unroll
                for (int kk = 0; kk < 2; ++kk)
                    acc[4 + mf][2 + nf] = __builtin_amdgcn_mfma_f32_16x16x32_bf16(a[mf][kk], b[1][nf][kk], acc[4 + mf][2 + nf], 0, 0, 0);
        __builtin_amdgcn_s_setprio(0);
        if (kt + 2 < NT) { asm volatile("s_waitcnt vmcnt(8)" ::: "memory"); }
        else             { asm volatile("s_waitcnt vmcnt(0)" ::: "memory"); }
        __builtin_amdgcn_s_barrier(); asm volatile("" ::: "memory");
    }

    const int orow = brow + wm * 128 + kh * 4;
    const int ocol = bcol + wn * 64 + r;
    if constexpr (EPI == MEPI_SPLIT_SILU) {
        u16* dst; int cb;
        if (bcol < EXPN) { dst = (u16*)O0; cb = ocol; }
        else             { dst = (u16*)O1; cb = ocol - EXPN; }
        #pragma unroll
        for (int Mf = 0; Mf < 8; ++Mf)
            #pragma unroll
            for (int Nf = 0; Nf < 4; ++Nf)
                #pragma unroll
                for (int j = 0; j < 4; ++j) {
                    const int row = orow + Mf * 16 + j;
                    const int col = ocol + Nf * 16;
                    float v = acc[Mf][Nf][j] + bias[col];
                    float sv = v * (1.f / (1.f + __expf(-v)));
                    dst[(size_t)row * EXPN + cb + Nf * 16] = f2b(sv);
                }
    } else {
        float* o = (float*)O0;
        #pragma unroll
        for (int Mf = 0; Mf < 8; ++Mf)
            #pragma unroll
            for (int Nf = 0; Nf < 4; ++Nf)
                #pragma unroll
                for (int j = 0; j < 4; ++j) {
                    const int row = orow + Mf * 16 + j;
                    const int col = ocol + Nf * 16;
                    o[(size_t)row * N + col] = acc[Mf][Nf][j] + bias[col] + res[(size_t)row * N + col];
                }
    }
}

// ---------------- 128x128 MFMA GEMM (m97 structure, BK=32) ----------------
template<int EPI>
__global__ __launch_bounds__(256)
void mgemm(const u16* __restrict__ A, const u16* __restrict__ Bt,
           const float* __restrict__ bias, void* __restrict__ O0,
           void* __restrict__ O1, const float* __restrict__ res,
           int N, int K) {
    __shared__ u16 As[128 * 32];
    __shared__ u16 Bs[128 * 32];
    const int tid  = threadIdx.x;
    const int wave = tid >> 6, lane = tid & 63;
    const int brow = blockIdx.y * 128, bcol = blockIdx.x * 128;
    const int wm = wave >> 1, wn = wave & 1;
    const int r  = lane & 15, kh = lane >> 4;

    f32x4 acc[4][4];
    #pragma unroll
    for (int m = 0; m < 4; m++)
        #pragma unroll
        for (int n = 0; n < 4; n++) acc[m][n] = (f32x4){0.f, 0.f, 0.f, 0.f};

    const u16* ga0 = A  + (size_t)(brow +      (tid >> 2)) * K + (tid & 3) * 8;
    const u16* ga1 = A  + (size_t)(brow + 64 + (tid >> 2)) * K + (tid & 3) * 8;
    const u16* gb0 = Bt + (size_t)(bcol +      (tid >> 2)) * K + (tid & 3) * 8;
    const u16* gb1 = Bt + (size_t)(bcol + 64 + (tid >> 2)) * K + (tid & 3) * 8;
    u16* lA0 = As + (wave * 64) * 8;
    u16* lA1 = As + (256 + wave * 64) * 8;
    u16* lB0 = Bs + (wave * 64) * 8;
    u16* lB1 = Bs + (256 + wave * 64) * 8;

    for (int k0 = 0; k0 < K; k0 += 32) {
        __syncthreads();
        __builtin_amdgcn_global_load_lds((const __attribute__((address_space(1))) void*)(ga0 + k0),
                                         (__attribute__((address_space(3))) void*)lA0, 16, 0, 0);
        __builtin_amdgcn_global_load_lds((const __attribute__((address_space(1))) void*)(ga1 + k0),
                                         (__attribute__((address_space(3))) void*)lA1, 16, 0, 0);
        __builtin_amdgcn_global_load_lds((const __attribute__((address_space(1))) void*)(gb0 + k0),
                                         (__attribute__((address_space(3))) void*)lB0, 16, 0, 0);
        __builtin_amdgcn_global_load_lds((const __attribute__((address_space(1))) void*)(gb1 + k0),
                                         (__attribute__((address_space(3))) void*)lB1, 16, 0, 0);
        __syncthreads();
        bf16x8 af[4], bfr[4];
        #pragma unroll
        for (int mf = 0; mf < 4; ++mf)
            af[mf] = *(const bf16x8*)(As + ((wm * 64 + mf * 16 + r) * 32 + kh * 8));
        #pragma unroll
        for (int nf = 0; nf < 4; ++nf)
            bfr[nf] = *(const bf16x8*)(Bs + ((wn * 64 + nf * 16 + r) * 32 + kh * 8));
        #pragma unroll
        for (int mf = 0; mf < 4; ++mf)
            #pragma unroll
            for (int nf = 0; nf < 4; ++nf)
                acc[mf][nf] = __builtin_amdgcn_mfma_f32_16x16x32_bf16(af[mf], bfr[nf], acc[mf][nf], 0, 0, 0);
    }

    const int orow = brow + wm * 64 + kh * 4;
    const int ocol = bcol + wn * 64 + r;
    if constexpr (EPI == MEPI_SPLIT_SILU) {
        u16* dst; int cb;
        if (bcol < EXPN) { dst = (u16*)O0; cb = ocol; }
        else             { dst = (u16*)O1; cb = ocol - EXPN; }
        #pragma unroll
        for (int mf = 0; mf < 4; ++mf)
            #pragma unroll
            for (int nf = 0; nf < 4; ++nf)
                #pragma unroll
                for (int j = 0; j < 4; ++j) {
                    const int row = orow + mf * 16 + j;
                    const int col = ocol + nf * 16;
                    float v = acc[mf][nf][j] + bias[col];
                    float sv = v * (1.f / (1.f + __expf(-v)));
                    dst[(size_t)row * EXPN + cb + nf * 16] = f2b(sv);
                }
    } else if constexpr (EPI == MEPI_SP) {
        u16* o = (u16*)O0;
        #pragma unroll
        for (int mf = 0; mf < 4; ++mf)
            #pragma unroll
            for (int nf = 0; nf < 4; ++nf)
                #pragma unroll
                for (int j = 0; j < 4; ++j) {
                    const int row = orow + mf * 16 + j;
                    const int col = ocol + nf * 16;
                    float v = acc[mf][nf][j] + bias[col];
                    // softplus via native log2/exp2 (guarded)
                    float sp = (v > 20.f) ? v
                             : 0.69314718056f * __builtin_amdgcn_logf(
                                   1.f + fexp2(1.44269504089f * v));
                    o[(size_t)row * N + col] = f2b(sp);
                }
    } else {
        float* o = (float*)O0;
        #pragma unroll
        for (int mf = 0; mf < 4; ++mf)
            #pragma unroll
            for (int nf = 0; nf < 4; ++nf)
                #pragma unroll
                for (int j = 0; j < 4; ++j) {
                    const int row = orow + mf * 16 + j;
                    const int col = ocol + nf * 16;
                    o[(size_t)row * N + col] = acc[mf][nf][j] + bias[col] + res[(size_t)row * N + col];
                }
    }
}

// ---------------- fused split-K projection: P = u @ Wcat^T (M x 96) ----------------
__global__ __launch_bounds__(256)
void k_proj(const u16* __restrict__ A, const u16* __restrict__ Wcat,
            float* __restrict__ Ppart) {
    __shared__ u16 As[128 * 32];
    __shared__ u16 Bs[96 * 32];
    const int tid  = threadIdx.x;
    const int wave = tid >> 6, lane = tid & 63;
    const int brow = blockIdx.y * 128;
    const int ks   = blockIdx.x;
    const int r = lane & 15, kh = lane >> 4;

    f32x4 acc[2][6];
    #pragma unroll
    for (int m = 0; m < 2; m++)
        #pragma unroll
        for (int n = 0; n < 6; n++) acc[m][n] = (f32x4){0.f, 0.f, 0.f, 0.f};

    const u16* ga0 = A + (size_t)(brow +      (tid >> 2)) * EXPN + ks * KCH + (tid & 3) * 8;
    const u16* ga1 = A + (size_t)(brow + 64 + (tid >> 2)) * EXPN + ks * KCH + (tid & 3) * 8;
    const u16* gb0 = Wcat + (size_t)(tid >> 2) * EXPN + ks * KCH + (tid & 3) * 8;
    const u16* gb1 = Wcat + (size_t)(64 + (tid >> 2)) * EXPN + ks * KCH + (tid & 3) * 8;
    u16* lA0 = As + (wave * 64) * 8;
    u16* lA1 = As + (256 + wave * 64) * 8;
    u16* lB0 = Bs + (wave * 64) * 8;
    u16* lB1 = Bs + (256 + wave * 64) * 8;

    for (int k0 = 0; k0 < KCH; k0 += 32) {
        __syncthreads();
        __builtin_amdgcn_global_load_lds((const __attribute__((address_space(1))) void*)(ga0 + k0),
                                         (__attribute__((address_space(3))) void*)lA0, 16, 0, 0);
        __builtin_amdgcn_global_load_lds((const __attribute__((address_space(1))) void*)(ga1 + k0),
                                         (__attribute__((address_space(3))) void*)lA1, 16, 0, 0);
        __builtin_amdgcn_global_load_lds((const __attribute__((address_space(1))) void*)(gb0 + k0),
                                         (__attribute__((address_space(3))) void*)lB0, 16, 0, 0);
        if (tid < 128)
            __builtin_amdgcn_global_load_lds((const __attribute__((address_space(1))) void*)(gb1 + k0),
                                             (__attribute__((address_space(3))) void*)lB1, 16, 0, 0);
        __syncthreads();
        bf16x8 af[2], bfr[6];
        #pragma unroll
        for (int mf = 0; mf < 2; ++mf)
            af[mf] = *(const bf16x8*)(As + ((wave * 32 + mf * 16 + r) * 32 + kh * 8));
        #pragma unroll
        for (int nf = 0; nf < 6; ++nf)
            bfr[nf] = *(const bf16x8*)(Bs + ((nf * 16 + r) * 32 + kh * 8));
        #pragma unroll
        for (int mf = 0; mf < 2; ++mf)
            #pragma unroll
            for (int nf = 0; nf < 6; ++nf)
                acc[mf][nf] = __builtin_amdgcn_mfma_f32_16x16x32_bf16(af[mf], bfr[nf], acc[mf][nf], 0, 0, 0);
    }
    const int orow = brow + wave * 32 + kh * 4;
    #pragma unroll
    for (int mf = 0; mf < 2; ++mf)
        #pragma unroll
        for (int nf = 0; nf < 6; ++nf)
            #pragma unroll
            for (int j = 0; j < 4; ++j)
                Ppart[((size_t)ks * MMN + orow + mf * 16 + j) * 96 + nf * 16 + r] = acc[mf][nf][j];
}

// ---------------- reduce split-K partials -> t1 (bf16), Bm, Cm (f32) ----------------
__global__ __launch_bounds__(192)
void k_red(const float* __restrict__ Ppart, const float* __restrict__ b_del,
           const float* __restrict__ b_B, const float* __restrict__ b_C,
           u16* __restrict__ t1b, float* __restrict__ Bm, float* __restrict__ Cm) {
    const int tid = threadIdx.x;
    const int ri  = tid / 96, col = tid - ri * 96;
    const int row = blockIdx.x * 2 + ri;
    float s = 0.f;
    #pragma unroll
    for (int ks = 0; ks < KSPL; ++ks)
        s += Ppart[((size_t)ks * MMN + row) * 96 + col];
    if (col < 64)      t1b[(size_t)row * DTRN + col] = f2b(s + b_del[col]);
    else if (col < 80) Bm[(size_t)row * SDIM + col - 64] = s + b_B[col - 64];
    else               Cm[(size_t)row * SDIM + col - 80] = s + b_C[col - 80];
}

// ---------------- chunked selective scan ----------------
__global__ __launch_bounds__(256)
void k_scan1(const u16* __restrict__ ub, const u16* __restrict__ db,
             const float* __restrict__ Bm, const float* __restrict__ A2,
             float* __restrict__ hend, float* __restrict__ Pp) {
    const int e = blockIdx.x * 256 + threadIdx.x;
    const int c = blockIdx.y, b = blockIdx.z;
    float a2[SDIM], h[SDIM];
    {
        const float4* ap = (const float4*)(A2 + (size_t)e * SDIM);
        float4 v0 = ap[0], v1 = ap[1], v2 = ap[2], v3 = ap[3];
        a2[0]=v0.x; a2[1]=v0.y; a2[2]=v0.z; a2[3]=v0.w;
        a2[4]=v1.x; a2[5]=v1.y; a2[6]=v1.z; a2[7]=v1.w;
        a2[8]=v2.x; a2[9]=v2.y; a2[10]=v2.z; a2[11]=v2.w;
        a2[12]=v3.x; a2[13]=v3.y; a2[14]=v3.z; a2[15]=v3.w;
    }
    #pragma unroll
    for (int s = 0; s < SDIM; s++) h[s] = 0.f;
    float sumd = 0.f;
    const int t0 = c * CLEN;
    size_t rb = ((size_t)b * TTN + t0) * EXPN + e;
    size_t bb_ = ((size_t)b * TTN + t0) * SDIM;
    for (int tt = 0; tt < CLEN; ++tt) {
        const float d  = b2f(db[rb]);
        const float uv = b2f(ub[rb]);
        const float4* bp = (const float4*)(Bm + bb_);
        float4 b0 = bp[0], b1 = bp[1], b2v = bp[2], b3 = bp[3];
        float bv[SDIM] = { b0.x,b0.y,b0.z,b0.w, b1.x,b1.y,b1.z,b1.w,
                           b2v.x,b2v.y,b2v.z,b2v.w, b3.x,b3.y,b3.z,b3.w };
        const float du = d * uv;
        sumd += d;
        #pragma unroll
        for (int s = 0; s < SDIM; ++s) {
            float ad = fexp2(d * a2[s]);
            h[s] = fmaf(ad, h[s], du * bv[s]);
        }
        rb += EXPN; bb_ += SDIM;
    }
    size_t ob = ((size_t)(b * NCHUNK + c) * SDIM) * EXPN + e;
    #pragma unroll
    for (int s = 0; s < SDIM; ++s) {
        hend[ob + (size_t)s * EXPN] = h[s];
        Pp  [ob + (size_t)s * EXPN] = fexp2(a2[s] * sumd);
    }
}

__global__ __launch_bounds__(256)
void k_fix(const float* __restrict__ hend, const float* __restrict__ Pp,
           float* __restrict__ hinit) {
    const int i = blockIdx.x * 256 + threadIdx.x;
    const int b = blockIdx.y;
    float hi = 0.f;
    size_t base = ((size_t)b * NCHUNK) * SDIM * EXPN + i;
    for (int cc = 0; cc < NCHUNK; ++cc) {
        size_t idx = base + (size_t)cc * SDIM * EXPN;
        hinit[idx] = hi;
        hi = fmaf(Pp[idx], hi, hend[idx]);
    }
}

__global__ __launch_bounds__(256)
void k_scan2(const u16* __restrict__ ub, const u16* __restrict__ db,
             const u16* __restrict__ sgb, const float* __restrict__ Bm,
             const float* __restrict__ Cm, const float* __restrict__ A2,
             const float* __restrict__ hinit, const float* __restrict__ Dp,
             u16* __restrict__ yb) {
    const int e = blockIdx.x * 256 + threadIdx.x;
    const int c = blockIdx.y, b = blockIdx.z;
    float a2[SDIM], h[SDIM];
    {
        const float4* ap = (const float4*)(A2 + (size_t)e * SDIM);
        float4 v0 = ap[0], v1 = ap[1], v2 = ap[2], v3 = ap[3];
        a2[0]=v0.x; a2[1]=v0.y; a2[2]=v0.z; a2[3]=v0.w;
        a2[4]=v1.x; a2[5]=v1.y; a2[6]=v1.z; a2[7]=v1.w;
        a2[8]=v2.x; a2[9]=v2.y; a2[10]=v2.z; a2[11]=v2.w;
        a2[12]=v3.x; a2[13]=v3.y; a2[14]=v3.z; a2[15]=v3.w;
    }
    {
        size_t hb = ((size_t)(b * NCHUNK + c) * SDIM) * EXPN + e;
        #pragma unroll
        for (int s = 0; s < SDIM; s++) h[s] = hinit[hb + (size_t)s * EXPN];
    }
    const float dpe = Dp[e];
    const int t0 = c * CLEN;
    size_t rb = ((size_t)b * TTN + t0) * EXPN + e;
    size_t bb_ = ((size_t)b * TTN + t0) * SDIM;
    for (int tt = 0; tt < CLEN; ++tt) {
        const float d   = b2f(db[rb]);
        const float uv  = b2f(ub[rb]);
        const float sgv = b2f(sgb[rb]);
        const float4* bp = (const float4*)(Bm + bb_);
        const float4* cp = (const float4*)(Cm + bb_);
        float4 b0 = bp[0], b1 = bp[1], b2v = bp[2], b3 = bp[3];
        float4 c0 = cp[0], c1 = cp[1], c2v = cp[2], c3 = cp[3];
        float bv[SDIM] = { b0.x,b0.y,b0.z,b0.w, b1.x,b1.y,b1.z,b1.w,
                           b2v.x,b2v.y,b2v.z,b2v.w, b3.x,b3.y,b3.z,b3.w };
        float cv[SDIM] = { c0.x,c0.y,c0.z,c0.w, c1.x,c1.y,c1.z,c1.w,
                           c2v.x,c2v.y,c2v.z,c2v.w, c3.x,c3.y,c3.z,c3.w };
        const float du = d * uv;
        float yt = 0.f;
        #pragma unroll
        for (int s = 0; s < SDIM; ++s) {
            float ad = fexp2(d * a2[s]);
            h[s] = fmaf(ad, h[s], du * bv[s]);
            yt = fmaf(cv[s], h[s], yt);
        }
        yb[rb] = f2b(fmaf(uv, dpe, yt) * sgv);
        rb += EXPN; bb_ += SDIM;
    }
}

// ---------------- launch ----------------
extern "C" void kernel_launch(void* const* d_in, const int* in_sizes, int n_in,
                              void* d_out, int out_size, void* d_ws, size_t ws_size,
                              hipStream_t stream) {
    const float* x     = (const float*)d_in[0];
    const float* ln_g  = (const float*)d_in[1];
    const float* ln_b  = (const float*)d_in[2];
    const float* W_in  = (const float*)d_in[3];
    const float* b_in  = (const float*)d_in[4];
    const float* W_del = (const float*)d_in[5];
    const float* b_del = (const float*)d_in[6];
    const float* W_dt  = (const float*)d_in[7];
    const float* b_dt  = (const float*)d_in[8];
    const float* W_B   = (const float*)d_in[9];
    const float* b_B   = (const float*)d_in[10];
    const float* W_C   = (const float*)d_in[11];
    const float* b_C   = (const float*)d_in[12];
    const float* A_log = (const float*)d_in[13];
    const float* Dp    = (const float*)d_in[14];
    const float* W_out = (const float*)d_in[15];
    const float* b_out = (const float*)d_in[16];
    float* out = (float*)d_out;

    char* p = (char*)d_ws;
    auto alloc = [&](size_t bytes) {
        char* r = p; p += (bytes + 255) & ~(size_t)255; return (void*)r;
    };
    u16* xn   = (u16*)alloc((size_t)MMN * HIDN * 2);
    u16* u    = (u16*)alloc((size_t)MMN * EXPN * 2);
    u16* sg   = (u16*)alloc((size_t)MMN * EXPN * 2);
    u16* dl   = (u16*)alloc((size_t)MMN * EXPN * 2);
    u16* y    = (u16*)alloc((size_t)MMN * EXPN * 2);
    u16* t1b  = (u16*)alloc((size_t)MMN * DTRN * 2);
    float* Bm = (float*)alloc((size_t)MMN * SDIM * 4);
    float* Cm = (float*)alloc((size_t)MMN * SDIM * 4);
    float* A2 = (float*)alloc((size_t)EXPN * SDIM * 4);
    u16* Wt_in  = (u16*)alloc((size_t)(2 * EXPN) * HIDN * 2);
    u16* Wt_out = (u16*)alloc((size_t)HIDN * EXPN * 2);
    u16* Wcat   = (u16*)alloc((size_t)96 * EXPN * 2);
    u16* Wdt_t  = (u16*)alloc((size_t)EXPN * DTRN * 2);
    const size_t hsz = (size_t)BBN * NCHUNK * EXPN * SDIM * 4;
    float* hend  = (float*)alloc(hsz);
    float* Pp    = (float*)alloc(hsz);
    float* hinit = (float*)alloc(hsz);
    float* Ppart = hend;   // aliased: consumed by k_red before scan1 writes

    k_prep<<<dim3(1024 + 512 + 32 + 768 + 128), 256, 0, stream>>>(
        W_in, W_out, W_dt, W_del, W_B, W_C, A_log, Wt_in, Wt_out, Wdt_t, Wcat, A2);
    k_ln<<<dim3(MMN), 256, 0, stream>>>(x, ln_g, ln_b, xn);

    // xp = xn @ W_in + b_in ; u = silu(left), sg = silu(right)  [256^2 8-phase]
    mgemm256<MEPI_SPLIT_SILU><<<dim3(2 * EXPN / 256, MMN / 256), 512, 0, stream>>>(
        xn, Wt_in, b_in, u, sg, nullptr, 2 * EXPN, HIDN);
    // fused projections: [t1|Bm|Cm] = u @ [W_del|W_B|W_C]   [MFMA split-K]
    k_proj<<<dim3(KSPL, MMN / 128), 256, 0, stream>>>(u, Wcat, Ppart);
    k_red<<<dim3(MMN / 2), 192, 0, stream>>>(Ppart, b_del, b_B, b_C, t1b, Bm, Cm);
    // delta = softplus(t1 @ W_dt + b_dt)   [MFMA 128^2]
    mgemm<MEPI_SP><<<dim3(EXPN / 128, MMN / 128), 256, 0, stream>>>(
        t1b, Wdt_t, b_dt, dl, nullptr, nullptr, EXPN, DTRN);
    // chunked selective scan
    k_scan1<<<dim3(EXPN / 256, NCHUNK, BBN), 256, 0, stream>>>(u, dl, Bm, A2, hend, Pp);
    k_fix<<<dim3(SDIM * EXPN / 256, BBN), 256, 0, stream>>>(hend, Pp, hinit);
    k_scan2<<<dim3(EXPN / 256, NCHUNK, BBN), 256, 0, stream>>>(u, dl, sg, Bm, Cm, A2, hinit, Dp, y);
    // out = y @ W_out + b_out + x   [MFMA 128^2]
    mgemm<MEPI_OUT><<<dim3(HIDN / 128, MMN / 128), 256, 0, stream>>>(
        y, Wt_out, b_out, out, nullptr, x, HIDN, EXPN);
}